// Round 1
// baseline (806.824 us; speedup 1.0000x reference)
//
#include <hip/hip_runtime.h>
#include <hip/hip_bf16.h>
#include <math.h>

#define NN 8192
#define DD 128
#define KK 128
#define EE 262144

// ---------------------------------------------------------------- activation
__device__ __forceinline__ float mishf(float v){
  // mish(v) = v * tanh(softplus(v)) = v * (e*(e+2))/(e*(e+2)+2), e = exp(v)
  float e  = __expf(v);
  float t2 = e * (e + 2.f);
  float r  = v * (t2 / (t2 + 2.f));
  return (v > 30.f) ? v : r;
}

// ---------------------------------------------------------------- CSR build
__global__ __launch_bounds__(256) void count_kernel(
    const int* __restrict__ eA, const int* __restrict__ eB,
    int* cntA, int* degA, int* cntB, int* degB){
  int g = blockIdx.y;
  const int* e  = g ? eB : eA;
  int* cnt = g ? cntB : cntA;
  int* deg = g ? degB : degA;
  const int* src = e;
  const int* dst = e + EE;
  int stride = gridDim.x * blockDim.x;
  for (int i = blockIdx.x * blockDim.x + threadIdx.x; i < EE; i += stride){
    atomicAdd(&cnt[dst[i]], 1);
    atomicAdd(&deg[src[i]], 1);
  }
}

__global__ __launch_bounds__(1024) void scan_kernel(
    const int* cntA, const int* cntB, int* rpA, int* rpB, int* curA, int* curB){
  int g = blockIdx.x;
  const int* cnt = g ? cntB : cntA;
  int* rp  = g ? rpB : rpA;
  int* cur = g ? curB : curA;
  __shared__ int sums[1024];
  int t = threadIdx.x;
  int v[8];
  int base = t * 8;
  int tot = 0;
#pragma unroll
  for (int j = 0; j < 8; ++j){ v[j] = cnt[base + j]; tot += v[j]; }
  sums[t] = tot; __syncthreads();
  for (int off = 1; off < 1024; off <<= 1){
    int x = 0;
    if (t >= off) x = sums[t - off];
    __syncthreads();
    sums[t] += x;
    __syncthreads();
  }
  int run = (t == 0) ? 0 : sums[t - 1];
#pragma unroll
  for (int j = 0; j < 8; ++j){ rp[base + j] = run; cur[base + j] = run; run += v[j]; }
  if (t == 1023) rp[NN] = run;
}

__global__ __launch_bounds__(256) void fill_csr(
    const int* __restrict__ eA, const int* __restrict__ eB,
    int* curA, int* curB, int* csrA, int* csrB){
  int g = blockIdx.y;
  const int* e = g ? eB : eA;
  int* cur = g ? curB : curA;
  int* csr = g ? csrB : csrA;
  const int* src = e;
  const int* dst = e + EE;
  int stride = gridDim.x * blockDim.x;
  for (int i = blockIdx.x * blockDim.x + threadIdx.x; i < EE; i += stride){
    int pos = atomicAdd(&cur[dst[i]], 1);
    csr[pos] = src[i];
  }
}

// ---------------------------------------------------------------- mean-aggregate
__global__ __launch_bounds__(256) void agg_mean(
    const int* __restrict__ rpA, const int* __restrict__ rpB,
    const int* __restrict__ csrA, const int* __restrict__ csrB,
    const float* __restrict__ XA, const float* __restrict__ XB,
    float* __restrict__ MA, float* __restrict__ MB){
  int g = blockIdx.y;
  const int* rp  = g ? rpB  : rpA;
  const int* csr = g ? csrB : csrA;
  const float* X = g ? XB : XA;
  float* M = g ? MB : MA;
  int t = threadIdx.x;
  int node = blockIdx.x * 8 + (t >> 5);
  int part = t & 31;
  int beg = rp[node], end = rp[node + 1];
  float ax = 0.f, ay = 0.f, az = 0.f, aw = 0.f;
  for (int j = beg; j < end; ++j){
    int s = csr[j];
    float4 v = *(const float4*)&X[s * DD + part * 4];
    ax += v.x; ay += v.y; az += v.z; aw += v.w;
  }
  float inv = 1.f / fmaxf((float)(end - beg), 1.f);
  float4 o; o.x = ax * inv; o.y = ay * inv; o.z = az * inv; o.w = aw * inv;
  *(float4*)&M[node * DD + part * 4] = o;
}

// ---------------------------------------------------------------- GEMM [N,128]@[128,128]
// out = A@Wa (+ B@Wb) + bias, ACT: 0 none, 1 mish, 2 row-softmax
template<int DUAL, int ACT>
__global__ __launch_bounds__(256) void gemm128(
    const float* __restrict__ A0, const float* __restrict__ A1,
    const float* __restrict__ B0, const float* __restrict__ B1,
    const float* __restrict__ Wa0, const float* __restrict__ Wa1,
    const float* __restrict__ Wb0, const float* __restrict__ Wb1,
    const float* __restrict__ bi0, const float* __restrict__ bi1,
    float* __restrict__ O0, float* __restrict__ O1){
  int g = blockIdx.y;
  const float* A  = g ? A1 : A0;
  const float* B  = g ? B1 : B0;
  const float* Wa = g ? Wa1 : Wa0;
  const float* Wb = g ? Wb1 : Wb0;
  const float* bi = g ? bi1 : bi0;
  float* O = g ? O1 : O0;

  __shared__ float As[64][36];
  __shared__ float Bs[DUAL ? 64 : 1][36];
  __shared__ float Was[32][132];
  __shared__ float Wbs[DUAL ? 32 : 1][132];

  int t = threadIdx.x;
  int tx = t & 15, ty = t >> 4;
  int rowBase = blockIdx.x * 64;

  float acc[4][8];
#pragma unroll
  for (int r = 0; r < 4; ++r)
#pragma unroll
    for (int c = 0; c < 8; ++c) acc[r][c] = 0.f;

  for (int kt = 0; kt < 128; kt += 32){
#pragma unroll
    for (int i = 0; i < 2; ++i){
      int idx = t * 2 + i;
      int r = idx >> 3, f = (idx & 7) * 4;
      *(float4*)&As[r][f] = *(const float4*)&A[(rowBase + r) * 128 + kt + f];
      if (DUAL) *(float4*)&Bs[r][f] = *(const float4*)&B[(rowBase + r) * 128 + kt + f];
    }
#pragma unroll
    for (int i = 0; i < 4; ++i){
      int idx = t * 4 + i;
      int r = idx >> 5, f = (idx & 31) * 4;
      *(float4*)&Was[r][f] = *(const float4*)&Wa[(kt + r) * 128 + f];
      if (DUAL) *(float4*)&Wbs[r][f] = *(const float4*)&Wb[(kt + r) * 128 + f];
    }
    __syncthreads();
#pragma unroll
    for (int kk = 0; kk < 32; ++kk){
      float wa[8], wb[8];
      *(float4*)&wa[0] = *(float4*)&Was[kk][tx * 8];
      *(float4*)&wa[4] = *(float4*)&Was[kk][tx * 8 + 4];
      if (DUAL){
        *(float4*)&wb[0] = *(float4*)&Wbs[kk][tx * 8];
        *(float4*)&wb[4] = *(float4*)&Wbs[kk][tx * 8 + 4];
      }
#pragma unroll
      for (int r = 0; r < 4; ++r){
        float a = As[ty * 4 + r][kk];
#pragma unroll
        for (int c = 0; c < 8; ++c) acc[r][c] += a * wa[c];
        if (DUAL){
          float b = Bs[ty * 4 + r][kk];
#pragma unroll
          for (int c = 0; c < 8; ++c) acc[r][c] += b * wb[c];
        }
      }
    }
    __syncthreads();
  }

  int colBase = tx * 8;
  float bv[8];
  *(float4*)&bv[0] = *(const float4*)&bi[colBase];
  *(float4*)&bv[4] = *(const float4*)&bi[colBase + 4];

#pragma unroll
  for (int r = 0; r < 4; ++r){
    float v[8];
#pragma unroll
    for (int c = 0; c < 8; ++c) v[c] = acc[r][c] + bv[c];
    if (ACT == 1){
#pragma unroll
      for (int c = 0; c < 8; ++c) v[c] = mishf(v[c]);
    }
    if (ACT == 2){
      float m = v[0];
#pragma unroll
      for (int c = 1; c < 8; ++c) m = fmaxf(m, v[c]);
      for (int msk = 1; msk < 16; msk <<= 1) m = fmaxf(m, __shfl_xor(m, msk));
      float sum = 0.f;
#pragma unroll
      for (int c = 0; c < 8; ++c){ v[c] = __expf(v[c] - m); sum += v[c]; }
      for (int msk = 1; msk < 16; msk <<= 1) sum += __shfl_xor(sum, msk);
      float inv = 1.f / sum;
#pragma unroll
      for (int c = 0; c < 8; ++c) v[c] *= inv;
    }
    int row = rowBase + ty * 4 + r;
    *(float4*)&O[row * 128 + colBase]     = make_float4(v[0], v[1], v[2], v[3]);
    *(float4*)&O[row * 128 + colBase + 4] = make_float4(v[4], v[5], v[6], v[7]);
  }
}

// ---------------------------------------------------------------- elementwise add (H += CO)
__global__ __launch_bounds__(256) void add_kernel(
    float* HA, float* HB, const float* CA, const float* CB){
  int g = blockIdx.y;
  float* H = g ? HB : HA;
  const float* C = g ? CB : CA;
  int idx = blockIdx.x * 256 + threadIdx.x;   // float4 index, 1024 blocks cover N*D/4
  float4 h = *(float4*)&H[idx * 4];
  float4 c = *(const float4*)&C[idx * 4];
  h.x += c.x; h.y += c.y; h.z += c.z; h.w += c.w;
  *(float4*)&H[idx * 4] = h;
}

// ---------------------------------------------------------------- pooled / ss outer products
// OUT[k,d] += sum_i P[i,k]*Q[i,d];  z=0: Q=H -> pooled, z=1: Q=S -> ss
__global__ __launch_bounds__(256) void pool_kernel(
    const float* S0, const float* S1, const float* H0, const float* H1,
    float* P0, float* P1, float* SS0, float* SS1){
  int g = blockIdx.y, z = blockIdx.z;
  const float* P = g ? S1 : S0;
  const float* Q = z ? (g ? S1 : S0) : (g ? H1 : H0);
  float* OUT = z ? (g ? SS1 : SS0) : (g ? P1 : P0);
  int t = threadIdx.x;
  int k = t & 127;
  int dh = (t >> 7) * 64;
  int i0 = blockIdx.x * 128;
  float acc[64];
#pragma unroll
  for (int d = 0; d < 64; ++d) acc[d] = 0.f;
  for (int i = i0; i < i0 + 128; ++i){
    float p = P[i * 128 + k];
    const float4* q = (const float4*)&Q[i * 128 + dh];
#pragma unroll
    for (int d4 = 0; d4 < 16; ++d4){
      float4 qv = q[d4];
      acc[d4 * 4 + 0] += p * qv.x;
      acc[d4 * 4 + 1] += p * qv.y;
      acc[d4 * 4 + 2] += p * qv.z;
      acc[d4 * 4 + 3] += p * qv.w;
    }
  }
  float* o = &OUT[k * 128 + dh];
#pragma unroll
  for (int d = 0; d < 64; ++d) atomicAdd(&o[d], acc[d]);
}

// ---------------------------------------------------------------- colsum + ca
__global__ __launch_bounds__(128) void colca_kernel(
    const float* S0, const float* S1, const int* dg0, const int* dg1,
    float* col0, float* col1, float* ca0, float* ca1){
  int g = blockIdx.y;
  const float* S = g ? S1 : S0;
  const int* dg = g ? dg1 : dg0;
  float* col = g ? col1 : col0;
  float* ca  = g ? ca1  : ca0;
  int k = threadIdx.x;
  int i0 = blockIdx.x * 128;
  float cs = 0.f, cc = 0.f;
  for (int i = i0; i < i0 + 128; ++i){
    float v = S[i * 128 + k];
    cs += v;
    cc += v * (float)dg[i];
  }
  atomicAdd(&col[k], cs);
  atomicAdd(&ca[k], cc);
}

// ---------------------------------------------------------------- trace(s^T adj s) over edges
__global__ __launch_bounds__(256) void trace_kernel(
    const int* eA, const int* eB, const float* S0, const float* S1,
    float* tr0, float* tr1){
  int g = blockIdx.y;
  const int* e = g ? eB : eA;
  const float* S = g ? S1 : S0;
  float* tr = g ? tr1 : tr0;
  const int* src = e;
  const int* dst = e + EE;
  int t = threadIdx.x;
  int lane = t & 63;
  int wid = blockIdx.x * 4 + (t >> 6);
  int nw = gridDim.x * 4;
  float part = 0.f;
  for (int i = wid; i < EE; i += nw){
    int a = src[i], b = dst[i];
    float2 va = *(const float2*)&S[a * 128 + lane * 2];
    float2 vb = *(const float2*)&S[b * 128 + lane * 2];
    part += va.x * vb.x + va.y * vb.y;
  }
  for (int msk = 1; msk < 64; msk <<= 1) part += __shfl_xor(part, msk);
  if (lane == 0) atomicAdd(tr, part);
}

// ---------------------------------------------------------------- losses
__device__ float block_reduce(float v, float* red, int t){
  red[t] = v; __syncthreads();
  for (int o = 128; o > 0; o >>= 1){
    if (t < o) red[t] += red[t + o];
    __syncthreads();
  }
  float r = red[0]; __syncthreads();
  return r;
}

__global__ __launch_bounds__(256) void finalize_kernel(
    const float* ss0, const float* ss1, const float* col0, const float* col1,
    const float* ca0, const float* ca1, const float* tr0, const float* tr1,
    float* loss_out){
  int g = blockIdx.x;
  const float* ss  = g ? ss1  : ss0;
  const float* col = g ? col1 : col0;
  const float* ca  = g ? ca1  : ca0;
  const float* tr  = g ? tr1  : tr0;
  __shared__ float red[256];
  int t = threadIdx.x;
  float s2 = 0.f;
  for (int i = t; i < 16384; i += 256){ float x = ss[i]; s2 += x * x; }
  float F2   = block_reduce(s2, red, t);
  float trss = block_reduce((t < 128) ? ss[t * 129] : 0.f, red, t);
  float ca2  = block_reduce((t < 128) ? ca[t] * ca[t] : 0.f, red, t);
  float cs2  = block_reduce((t < 128) ? col[t] * col[t] : 0.f, red, t);
  if (t == 0){
    float F = sqrtf(F2);
    float ortho = sqrtf(fmaxf(2.f - 2.f * trss / (F * sqrtf((float)KK)), 0.f));
    float m2 = (float)EE;                 // 2m
    float spectral = -(tr[0] - ca2 / m2) / m2;
    float cluster = sqrtf(cs2) / (float)NN * sqrtf((float)KK) - 1.f;
    atomicAdd(loss_out, spectral + ortho + cluster);
  }
}

// ---------------------------------------------------------------- selu + store pooled
__global__ __launch_bounds__(256) void selu_kernel(
    const float* p0, const float* p1, float* out){
  int g = blockIdx.y;
  const float* p = g ? p1 : p0;
  int idx = blockIdx.x * 256 + threadIdx.x;  // 64 blocks x 256 = 16384
  float v = p[idx];
  const float scale = 1.0507009873554805f, alpha = 1.6732632423543772f;
  float r = (v > 0.f) ? scale * v : scale * alpha * expm1f(v);
  out[g * 16384 + idx] = r;
}

// ---------------------------------------------------------------- launch
extern "C" void kernel_launch(void* const* d_in, const int* in_sizes, int n_in,
                              void* d_out, int out_size, void* d_ws, size_t ws_size,
                              hipStream_t stream){
  const float* x1 = (const float*)d_in[0];
  const float* x2 = (const float*)d_in[1];
  const int*   e1 = (const int*)d_in[2];
  const int*   e2 = (const int*)d_in[3];
  const float* c1_Wl = (const float*)d_in[4];
  const float* c1_bl = (const float*)d_in[5];
  const float* c1_Wr = (const float*)d_in[6];
  const float* c2_Wl = (const float*)d_in[7];
  const float* c2_bl = (const float*)d_in[8];
  const float* c2_Wr = (const float*)d_in[9];
  const float* co_Wl = (const float*)d_in[10];
  const float* co_bl = (const float*)d_in[11];
  const float* co_Wr = (const float*)d_in[12];
  const float* c3_Wl = (const float*)d_in[13];
  const float* c3_bl = (const float*)d_in[14];
  const float* c3_Wr = (const float*)d_in[15];
  const float* c4_Wl = (const float*)d_in[16];
  const float* c4_bl = (const float*)d_in[17];
  const float* c4_Wr = (const float*)d_in[18];
  const float* m_W1 = (const float*)d_in[19];
  const float* m_b1 = (const float*)d_in[20];
  const float* m_W2 = (const float*)d_in[21];
  const float* m_b2 = (const float*)d_in[22];
  float* out = (float*)d_out;

  char* w = (char*)d_ws;
  auto alloc = [&](size_t bytes) -> char* {
    char* p = w;
    w += (bytes + 255) / 256 * 256;
    return p;
  };
  // zero region A: counts
  int* cnt0 = (int*)alloc(NN * 4);
  int* deg0 = (int*)alloc(NN * 4);
  int* cnt1 = (int*)alloc(NN * 4);
  int* deg1 = (int*)alloc(NN * 4);
  size_t zeroA_len = (size_t)(w - (char*)cnt0);
  // zero region B: accumulators
  float* pooled0 = (float*)alloc(16384 * 4);
  float* ss0     = (float*)alloc(16384 * 4);
  float* col0    = (float*)alloc(128 * 4);
  float* ca0     = (float*)alloc(128 * 4);
  float* tr0     = (float*)alloc(256);
  float* pooled1 = (float*)alloc(16384 * 4);
  float* ss1     = (float*)alloc(16384 * 4);
  float* col1    = (float*)alloc(128 * 4);
  float* ca1     = (float*)alloc(128 * 4);
  float* tr1     = (float*)alloc(256);
  size_t zeroB_len = (size_t)(w - (char*)pooled0);
  // CSR
  int* rp0  = (int*)alloc((NN + 1) * 4);
  int* cur0 = (int*)alloc(NN * 4);
  int* csr0 = (int*)alloc(EE * 4);
  int* rp1  = (int*)alloc((NN + 1) * 4);
  int* cur1 = (int*)alloc(NN * 4);
  int* csr1 = (int*)alloc(EE * 4);
  // feature buffers
  float* H0   = (float*)alloc((size_t)NN * DD * 4);
  float* AGG0 = (float*)alloc((size_t)NN * DD * 4);
  float* CO0  = (float*)alloc((size_t)NN * DD * 4);
  float* S0   = (float*)alloc((size_t)NN * DD * 4);
  float* H1   = (float*)alloc((size_t)NN * DD * 4);
  float* AGG1 = (float*)alloc((size_t)NN * DD * 4);
  float* CO1  = (float*)alloc((size_t)NN * DD * 4);
  float* S1   = (float*)alloc((size_t)NN * DD * 4);

  hipMemsetAsync(cnt0, 0, zeroA_len, stream);
  hipMemsetAsync(pooled0, 0, zeroB_len, stream);
  hipMemsetAsync(out + 32768, 0, 4, stream);

  // CSR build (both graphs)
  count_kernel<<<dim3(256, 2), 256, 0, stream>>>(e1, e2, cnt0, deg0, cnt1, deg1);
  scan_kernel<<<2, 1024, 0, stream>>>(cnt0, cnt1, rp0, rp1, cur0, cur1);
  fill_csr<<<dim3(256, 2), 256, 0, stream>>>(e1, e2, cur0, cur1, csr0, csr1);

  // sage1: h = mish(mean@Wl + x@Wr + bl)
  agg_mean<<<dim3(1024, 2), 256, 0, stream>>>(rp0, rp1, csr0, csr1, x1, x2, AGG0, AGG1);
  gemm128<1, 1><<<dim3(128, 2), 256, 0, stream>>>(AGG0, AGG1, x1, x2,
      c1_Wl, c2_Wl, c1_Wr, c2_Wr, c1_bl, c2_bl, H0, H1);

  // sage2 (shared co weights): co = mish(sage(h))
  agg_mean<<<dim3(1024, 2), 256, 0, stream>>>(rp0, rp1, csr0, csr1, H0, H1, AGG0, AGG1);
  gemm128<1, 1><<<dim3(128, 2), 256, 0, stream>>>(AGG0, AGG1, H0, H1,
      co_Wl, co_Wl, co_Wr, co_Wr, co_bl, co_bl, CO0, CO1);

  // z = h + co (in place into H)
  add_kernel<<<dim3(1024, 2), 256, 0, stream>>>(H0, H1, CO0, CO1);

  // sage3: h_final = mish(sage(z)) -> CO
  agg_mean<<<dim3(1024, 2), 256, 0, stream>>>(rp0, rp1, csr0, csr1, H0, H1, AGG0, AGG1);
  gemm128<1, 1><<<dim3(128, 2), 256, 0, stream>>>(AGG0, AGG1, H0, H1,
      c3_Wl, c4_Wl, c3_Wr, c4_Wr, c3_bl, c4_bl, CO0, CO1);

  // dmon MLP: t = h@W1+b1 (AGG reused as tmp), s = softmax(t@W2+b2)
  gemm128<0, 0><<<dim3(128, 2), 256, 0, stream>>>(CO0, CO1, nullptr, nullptr,
      m_W1, m_W1, nullptr, nullptr, m_b1, m_b1, AGG0, AGG1);
  gemm128<0, 2><<<dim3(128, 2), 256, 0, stream>>>(AGG0, AGG1, nullptr, nullptr,
      m_W2, m_W2, nullptr, nullptr, m_b2, m_b2, S0, S1);

  // pooled = s^T h ; ss = s^T s
  pool_kernel<<<dim3(64, 2, 2), 256, 0, stream>>>(S0, S1, CO0, CO1,
      pooled0, pooled1, ss0, ss1);
  colca_kernel<<<dim3(64, 2), 128, 0, stream>>>(S0, S1, deg0, deg1, col0, col1, ca0, ca1);
  trace_kernel<<<dim3(256, 2), 256, 0, stream>>>(e1, e2, S0, S1, tr0, tr1);

  finalize_kernel<<<2, 256, 0, stream>>>(ss0, ss1, col0, col1, ca0, ca1, tr0, tr1,
      out + 32768);
  selu_kernel<<<dim3(64, 2), 256, 0, stream>>>(pooled0, pooled1, out);
}

// Round 2
// 523.401 us; speedup vs baseline: 1.5415x; 1.5415x over previous
//
#include <hip/hip_runtime.h>
#include <hip/hip_bf16.h>
#include <math.h>

#define NN 8192
#define DD 128
#define KK 128
#define EE 262144

// ---------------------------------------------------------------- activation
__device__ __forceinline__ float mishf(float v){
  // mish(v) = v * tanh(softplus(v)) = v * (e*(e+2))/(e*(e+2)+2), e = exp(v)
  float e  = __expf(v);
  float t2 = e * (e + 2.f);
  float r  = v * (t2 / (t2 + 2.f));
  return (v > 30.f) ? v : r;
}

// ---------------------------------------------------------------- CSR build
__global__ __launch_bounds__(256) void count_kernel(
    const int* __restrict__ eA, const int* __restrict__ eB,
    int* cntA, int* degA, int* cntB, int* degB){
  int g = blockIdx.y;
  const int* e  = g ? eB : eA;
  int* cnt = g ? cntB : cntA;
  int* deg = g ? degB : degA;
  const int* src = e;
  const int* dst = e + EE;
  int stride = gridDim.x * blockDim.x;
  for (int i = blockIdx.x * blockDim.x + threadIdx.x; i < EE; i += stride){
    atomicAdd(&cnt[dst[i]], 1);
    atomicAdd(&deg[src[i]], 1);
  }
}

__global__ __launch_bounds__(1024) void scan_kernel(
    const int* cntA, const int* cntB, int* rpA, int* rpB, int* curA, int* curB){
  int g = blockIdx.x;
  const int* cnt = g ? cntB : cntA;
  int* rp  = g ? rpB : rpA;
  int* cur = g ? curB : curA;
  __shared__ int sums[1024];
  int t = threadIdx.x;
  int v[8];
  int base = t * 8;
  int tot = 0;
#pragma unroll
  for (int j = 0; j < 8; ++j){ v[j] = cnt[base + j]; tot += v[j]; }
  sums[t] = tot; __syncthreads();
  for (int off = 1; off < 1024; off <<= 1){
    int x = 0;
    if (t >= off) x = sums[t - off];
    __syncthreads();
    sums[t] += x;
    __syncthreads();
  }
  int run = (t == 0) ? 0 : sums[t - 1];
#pragma unroll
  for (int j = 0; j < 8; ++j){ rp[base + j] = run; cur[base + j] = run; run += v[j]; }
  if (t == 1023) rp[NN] = run;
}

__global__ __launch_bounds__(256) void fill_csr(
    const int* __restrict__ eA, const int* __restrict__ eB,
    int* curA, int* curB, int* csrA, int* csrB){
  int g = blockIdx.y;
  const int* e = g ? eB : eA;
  int* cur = g ? curB : curA;
  int* csr = g ? csrB : csrA;
  const int* src = e;
  const int* dst = e + EE;
  int stride = gridDim.x * blockDim.x;
  for (int i = blockIdx.x * blockDim.x + threadIdx.x; i < EE; i += stride){
    int pos = atomicAdd(&cur[dst[i]], 1);
    csr[pos] = src[i];
  }
}

// ---------------------------------------------------------------- mean-aggregate
__global__ __launch_bounds__(256) void agg_mean(
    const int* __restrict__ rpA, const int* __restrict__ rpB,
    const int* __restrict__ csrA, const int* __restrict__ csrB,
    const float* __restrict__ XA, const float* __restrict__ XB,
    float* __restrict__ MA, float* __restrict__ MB){
  int g = blockIdx.y;
  const int* rp  = g ? rpB  : rpA;
  const int* csr = g ? csrB : csrA;
  const float* X = g ? XB : XA;
  float* M = g ? MB : MA;
  int t = threadIdx.x;
  int node = blockIdx.x * 8 + (t >> 5);
  int part = t & 31;
  int beg = rp[node], end = rp[node + 1];
  float ax = 0.f, ay = 0.f, az = 0.f, aw = 0.f;
  for (int j = beg; j < end; ++j){
    int s = csr[j];
    float4 v = *(const float4*)&X[s * DD + part * 4];
    ax += v.x; ay += v.y; az += v.z; aw += v.w;
  }
  float inv = 1.f / fmaxf((float)(end - beg), 1.f);
  float4 o; o.x = ax * inv; o.y = ay * inv; o.z = az * inv; o.w = aw * inv;
  *(float4*)&M[node * DD + part * 4] = o;
}

// ---------------------------------------------------------------- GEMM [N,128]@[128,128]
// out = A@Wa (+ B@Wb) + bias, ACT: 0 none, 1 mish, 2 row-softmax
template<int DUAL, int ACT>
__global__ __launch_bounds__(256) void gemm128(
    const float* __restrict__ A0, const float* __restrict__ A1,
    const float* __restrict__ B0, const float* __restrict__ B1,
    const float* __restrict__ Wa0, const float* __restrict__ Wa1,
    const float* __restrict__ Wb0, const float* __restrict__ Wb1,
    const float* __restrict__ bi0, const float* __restrict__ bi1,
    float* __restrict__ O0, float* __restrict__ O1){
  int g = blockIdx.y;
  const float* A  = g ? A1 : A0;
  const float* B  = g ? B1 : B0;
  const float* Wa = g ? Wa1 : Wa0;
  const float* Wb = g ? Wb1 : Wb0;
  const float* bi = g ? bi1 : bi0;
  float* O = g ? O1 : O0;

  __shared__ float As[64][36];
  __shared__ float Bs[DUAL ? 64 : 1][36];
  __shared__ float Was[32][132];
  __shared__ float Wbs[DUAL ? 32 : 1][132];

  int t = threadIdx.x;
  int tx = t & 15, ty = t >> 4;
  int rowBase = blockIdx.x * 64;

  float acc[4][8];
#pragma unroll
  for (int r = 0; r < 4; ++r)
#pragma unroll
    for (int c = 0; c < 8; ++c) acc[r][c] = 0.f;

  for (int kt = 0; kt < 128; kt += 32){
#pragma unroll
    for (int i = 0; i < 2; ++i){
      int idx = t * 2 + i;
      int r = idx >> 3, f = (idx & 7) * 4;
      *(float4*)&As[r][f] = *(const float4*)&A[(rowBase + r) * 128 + kt + f];
      if (DUAL) *(float4*)&Bs[r][f] = *(const float4*)&B[(rowBase + r) * 128 + kt + f];
    }
#pragma unroll
    for (int i = 0; i < 4; ++i){
      int idx = t * 4 + i;
      int r = idx >> 5, f = (idx & 31) * 4;
      *(float4*)&Was[r][f] = *(const float4*)&Wa[(kt + r) * 128 + f];
      if (DUAL) *(float4*)&Wbs[r][f] = *(const float4*)&Wb[(kt + r) * 128 + f];
    }
    __syncthreads();
#pragma unroll
    for (int kk = 0; kk < 32; ++kk){
      float wa[8], wb[8];
      *(float4*)&wa[0] = *(float4*)&Was[kk][tx * 8];
      *(float4*)&wa[4] = *(float4*)&Was[kk][tx * 8 + 4];
      if (DUAL){
        *(float4*)&wb[0] = *(float4*)&Wbs[kk][tx * 8];
        *(float4*)&wb[4] = *(float4*)&Wbs[kk][tx * 8 + 4];
      }
#pragma unroll
      for (int r = 0; r < 4; ++r){
        float a = As[ty * 4 + r][kk];
#pragma unroll
        for (int c = 0; c < 8; ++c) acc[r][c] += a * wa[c];
        if (DUAL){
          float b = Bs[ty * 4 + r][kk];
#pragma unroll
          for (int c = 0; c < 8; ++c) acc[r][c] += b * wb[c];
        }
      }
    }
    __syncthreads();
  }

  int colBase = tx * 8;
  float bv[8];
  *(float4*)&bv[0] = *(const float4*)&bi[colBase];
  *(float4*)&bv[4] = *(const float4*)&bi[colBase + 4];

#pragma unroll
  for (int r = 0; r < 4; ++r){
    float v[8];
#pragma unroll
    for (int c = 0; c < 8; ++c) v[c] = acc[r][c] + bv[c];
    if (ACT == 1){
#pragma unroll
      for (int c = 0; c < 8; ++c) v[c] = mishf(v[c]);
    }
    if (ACT == 2){
      float m = v[0];
#pragma unroll
      for (int c = 1; c < 8; ++c) m = fmaxf(m, v[c]);
      for (int msk = 1; msk < 16; msk <<= 1) m = fmaxf(m, __shfl_xor(m, msk));
      float sum = 0.f;
#pragma unroll
      for (int c = 0; c < 8; ++c){ v[c] = __expf(v[c] - m); sum += v[c]; }
      for (int msk = 1; msk < 16; msk <<= 1) sum += __shfl_xor(sum, msk);
      float inv = 1.f / sum;
#pragma unroll
      for (int c = 0; c < 8; ++c) v[c] *= inv;
    }
    int row = rowBase + ty * 4 + r;
    *(float4*)&O[row * 128 + colBase]     = make_float4(v[0], v[1], v[2], v[3]);
    *(float4*)&O[row * 128 + colBase + 4] = make_float4(v[4], v[5], v[6], v[7]);
  }
}

// ---------------------------------------------------------------- elementwise add (H += CO)
__global__ __launch_bounds__(256) void add_kernel(
    float* HA, float* HB, const float* CA, const float* CB){
  int g = blockIdx.y;
  float* H = g ? HB : HA;
  const float* C = g ? CB : CA;
  int idx = blockIdx.x * 256 + threadIdx.x;   // float4 index, 1024 blocks cover N*D/4
  float4 h = *(float4*)&H[idx * 4];
  float4 c = *(const float4*)&C[idx * 4];
  h.x += c.x; h.y += c.y; h.z += c.z; h.w += c.w;
  *(float4*)&H[idx * 4] = h;
}

// ---------------------------------------------------------------- pooled / ss outer products
// OUT[k,d] += sum_i P[i,k]*Q[i,d];  z=0: Q=H -> pooled, z=1: Q=S -> ss
// Split-K GEMM: block = one 64x64 quadrant of the 128x128 output, 512-row K split.
// 16x16 threads, 4x4 register tile per thread (acc stays in VGPRs, no scratch).
#define PK_NSPLIT 16
__global__ __launch_bounds__(256) void pool_kernel(
    const float* __restrict__ S0, const float* __restrict__ S1,
    const float* __restrict__ H0, const float* __restrict__ H1,
    float* P0, float* P1, float* SS0, float* SS1){
  int g = blockIdx.y, z = blockIdx.z;
  const float* S = g ? S1 : S0;
  const float* Q = z ? S : (g ? H1 : H0);
  float* OUT = z ? (g ? SS1 : SS0) : (g ? P1 : P0);

  int quad  = blockIdx.x & 3;       // (qk, qd) quadrant of 128x128 output
  int split = blockIdx.x >> 2;      // 0..PK_NSPLIT-1
  int k0 = (quad >> 1) * 64;
  int d0 = (quad & 1) * 64;

  __shared__ float St[64][33];      // S chunk, transposed: St[kk][i]
  __shared__ float Qs[32][68];      // Q chunk, row-major

  int t = threadIdx.x;
  int tx = t & 15, ty = t >> 4;

  float acc[4][4];
#pragma unroll
  for (int r = 0; r < 4; ++r)
#pragma unroll
    for (int c = 0; c < 4; ++c) acc[r][c] = 0.f;

  int i0base = split * (NN / PK_NSPLIT);
  for (int chunk = 0; chunk < (NN / PK_NSPLIT) / 32; ++chunk){
    int i0 = i0base + chunk * 32;
    __syncthreads();
#pragma unroll
    for (int j = 0; j < 2; ++j){
      int idx = t + j * 256;
      int row = idx >> 4, f4 = (idx & 15) * 4;
      float4 sv = *(const float4*)&S[(i0 + row) * 128 + k0 + f4];
      St[f4 + 0][row] = sv.x;
      St[f4 + 1][row] = sv.y;
      St[f4 + 2][row] = sv.z;
      St[f4 + 3][row] = sv.w;
      *(float4*)&Qs[row][f4] = *(const float4*)&Q[(i0 + row) * 128 + d0 + f4];
    }
    __syncthreads();
#pragma unroll 8
    for (int i = 0; i < 32; ++i){
      float4 qv = *(float4*)&Qs[i][tx * 4];
      float s0 = St[ty * 4 + 0][i];
      float s1 = St[ty * 4 + 1][i];
      float s2 = St[ty * 4 + 2][i];
      float s3 = St[ty * 4 + 3][i];
      acc[0][0] += s0 * qv.x; acc[0][1] += s0 * qv.y; acc[0][2] += s0 * qv.z; acc[0][3] += s0 * qv.w;
      acc[1][0] += s1 * qv.x; acc[1][1] += s1 * qv.y; acc[1][2] += s1 * qv.z; acc[1][3] += s1 * qv.w;
      acc[2][0] += s2 * qv.x; acc[2][1] += s2 * qv.y; acc[2][2] += s2 * qv.z; acc[2][3] += s2 * qv.w;
      acc[3][0] += s3 * qv.x; acc[3][1] += s3 * qv.y; acc[3][2] += s3 * qv.z; acc[3][3] += s3 * qv.w;
    }
  }

  int k = k0 + ty * 4, d = d0 + tx * 4;
#pragma unroll
  for (int r = 0; r < 4; ++r)
#pragma unroll
    for (int c = 0; c < 4; ++c)
      atomicAdd(&OUT[(k + r) * 128 + d + c], acc[r][c]);
}

// ---------------------------------------------------------------- colsum + ca
__global__ __launch_bounds__(128) void colca_kernel(
    const float* S0, const float* S1, const int* dg0, const int* dg1,
    float* col0, float* col1, float* ca0, float* ca1){
  int g = blockIdx.y;
  const float* S = g ? S1 : S0;
  const int* dg = g ? dg1 : dg0;
  float* col = g ? col1 : col0;
  float* ca  = g ? ca1  : ca0;
  int k = threadIdx.x;
  int i0 = blockIdx.x * 128;
  float cs = 0.f, cc = 0.f;
  for (int i = i0; i < i0 + 128; ++i){
    float v = S[i * 128 + k];
    cs += v;
    cc += v * (float)dg[i];
  }
  atomicAdd(&col[k], cs);
  atomicAdd(&ca[k], cc);
}

// ---------------------------------------------------------------- trace(s^T adj s) over edges
__global__ __launch_bounds__(256) void trace_kernel(
    const int* eA, const int* eB, const float* S0, const float* S1,
    float* tr0, float* tr1){
  int g = blockIdx.y;
  const int* e = g ? eB : eA;
  const float* S = g ? S1 : S0;
  float* tr = g ? tr1 : tr0;
  const int* src = e;
  const int* dst = e + EE;
  int t = threadIdx.x;
  int lane = t & 63;
  int wid = blockIdx.x * 4 + (t >> 6);
  int nw = gridDim.x * 4;
  float part = 0.f;
  for (int i = wid; i < EE; i += nw){
    int a = src[i], b = dst[i];
    float2 va = *(const float2*)&S[a * 128 + lane * 2];
    float2 vb = *(const float2*)&S[b * 128 + lane * 2];
    part += va.x * vb.x + va.y * vb.y;
  }
  for (int msk = 1; msk < 64; msk <<= 1) part += __shfl_xor(part, msk);
  if (lane == 0) atomicAdd(tr, part);
}

// ---------------------------------------------------------------- losses
__device__ float block_reduce(float v, float* red, int t){
  red[t] = v; __syncthreads();
  for (int o = 128; o > 0; o >>= 1){
    if (t < o) red[t] += red[t + o];
    __syncthreads();
  }
  float r = red[0]; __syncthreads();
  return r;
}

__global__ __launch_bounds__(256) void finalize_kernel(
    const float* ss0, const float* ss1, const float* col0, const float* col1,
    const float* ca0, const float* ca1, const float* tr0, const float* tr1,
    float* loss_out){
  int g = blockIdx.x;
  const float* ss  = g ? ss1  : ss0;
  const float* col = g ? col1 : col0;
  const float* ca  = g ? ca1  : ca0;
  const float* tr  = g ? tr1  : tr0;
  __shared__ float red[256];
  int t = threadIdx.x;
  float s2 = 0.f;
  for (int i = t; i < 16384; i += 256){ float x = ss[i]; s2 += x * x; }
  float F2   = block_reduce(s2, red, t);
  float trss = block_reduce((t < 128) ? ss[t * 129] : 0.f, red, t);
  float ca2  = block_reduce((t < 128) ? ca[t] * ca[t] : 0.f, red, t);
  float cs2  = block_reduce((t < 128) ? col[t] * col[t] : 0.f, red, t);
  if (t == 0){
    float F = sqrtf(F2);
    float ortho = sqrtf(fmaxf(2.f - 2.f * trss / (F * sqrtf((float)KK)), 0.f));
    float m2 = (float)EE;                 // 2m
    float spectral = -(tr[0] - ca2 / m2) / m2;
    float cluster = sqrtf(cs2) / (float)NN * sqrtf((float)KK) - 1.f;
    atomicAdd(loss_out, spectral + ortho + cluster);
  }
}

// ---------------------------------------------------------------- selu + store pooled
__global__ __launch_bounds__(256) void selu_kernel(
    const float* p0, const float* p1, float* out){
  int g = blockIdx.y;
  const float* p = g ? p1 : p0;
  int idx = blockIdx.x * 256 + threadIdx.x;  // 64 blocks x 256 = 16384
  float v = p[idx];
  const float scale = 1.0507009873554805f, alpha = 1.6732632423543772f;
  float r = (v > 0.f) ? scale * v : scale * alpha * expm1f(v);
  out[g * 16384 + idx] = r;
}

// ---------------------------------------------------------------- launch
extern "C" void kernel_launch(void* const* d_in, const int* in_sizes, int n_in,
                              void* d_out, int out_size, void* d_ws, size_t ws_size,
                              hipStream_t stream){
  const float* x1 = (const float*)d_in[0];
  const float* x2 = (const float*)d_in[1];
  const int*   e1 = (const int*)d_in[2];
  const int*   e2 = (const int*)d_in[3];
  const float* c1_Wl = (const float*)d_in[4];
  const float* c1_bl = (const float*)d_in[5];
  const float* c1_Wr = (const float*)d_in[6];
  const float* c2_Wl = (const float*)d_in[7];
  const float* c2_bl = (const float*)d_in[8];
  const float* c2_Wr = (const float*)d_in[9];
  const float* co_Wl = (const float*)d_in[10];
  const float* co_bl = (const float*)d_in[11];
  const float* co_Wr = (const float*)d_in[12];
  const float* c3_Wl = (const float*)d_in[13];
  const float* c3_bl = (const float*)d_in[14];
  const float* c3_Wr = (const float*)d_in[15];
  const float* c4_Wl = (const float*)d_in[16];
  const float* c4_bl = (const float*)d_in[17];
  const float* c4_Wr = (const float*)d_in[18];
  const float* m_W1 = (const float*)d_in[19];
  const float* m_b1 = (const float*)d_in[20];
  const float* m_W2 = (const float*)d_in[21];
  const float* m_b2 = (const float*)d_in[22];
  float* out = (float*)d_out;

  char* w = (char*)d_ws;
  auto alloc = [&](size_t bytes) -> char* {
    char* p = w;
    w += (bytes + 255) / 256 * 256;
    return p;
  };
  // zero region A: counts
  int* cnt0 = (int*)alloc(NN * 4);
  int* deg0 = (int*)alloc(NN * 4);
  int* cnt1 = (int*)alloc(NN * 4);
  int* deg1 = (int*)alloc(NN * 4);
  size_t zeroA_len = (size_t)(w - (char*)cnt0);
  // zero region B: accumulators
  float* pooled0 = (float*)alloc(16384 * 4);
  float* ss0     = (float*)alloc(16384 * 4);
  float* col0    = (float*)alloc(128 * 4);
  float* ca0     = (float*)alloc(128 * 4);
  float* tr0     = (float*)alloc(256);
  float* pooled1 = (float*)alloc(16384 * 4);
  float* ss1     = (float*)alloc(16384 * 4);
  float* col1    = (float*)alloc(128 * 4);
  float* ca1     = (float*)alloc(128 * 4);
  float* tr1     = (float*)alloc(256);
  size_t zeroB_len = (size_t)(w - (char*)pooled0);
  // CSR
  int* rp0  = (int*)alloc((NN + 1) * 4);
  int* cur0 = (int*)alloc(NN * 4);
  int* csr0 = (int*)alloc(EE * 4);
  int* rp1  = (int*)alloc((NN + 1) * 4);
  int* cur1 = (int*)alloc(NN * 4);
  int* csr1 = (int*)alloc(EE * 4);
  // feature buffers
  float* H0   = (float*)alloc((size_t)NN * DD * 4);
  float* AGG0 = (float*)alloc((size_t)NN * DD * 4);
  float* CO0  = (float*)alloc((size_t)NN * DD * 4);
  float* S0   = (float*)alloc((size_t)NN * DD * 4);
  float* H1   = (float*)alloc((size_t)NN * DD * 4);
  float* AGG1 = (float*)alloc((size_t)NN * DD * 4);
  float* CO1  = (float*)alloc((size_t)NN * DD * 4);
  float* S1   = (float*)alloc((size_t)NN * DD * 4);

  hipMemsetAsync(cnt0, 0, zeroA_len, stream);
  hipMemsetAsync(pooled0, 0, zeroB_len, stream);
  hipMemsetAsync(out + 32768, 0, 4, stream);

  // CSR build (both graphs)
  count_kernel<<<dim3(256, 2), 256, 0, stream>>>(e1, e2, cnt0, deg0, cnt1, deg1);
  scan_kernel<<<2, 1024, 0, stream>>>(cnt0, cnt1, rp0, rp1, cur0, cur1);
  fill_csr<<<dim3(256, 2), 256, 0, stream>>>(e1, e2, cur0, cur1, csr0, csr1);

  // sage1: h = mish(mean@Wl + x@Wr + bl)
  agg_mean<<<dim3(1024, 2), 256, 0, stream>>>(rp0, rp1, csr0, csr1, x1, x2, AGG0, AGG1);
  gemm128<1, 1><<<dim3(128, 2), 256, 0, stream>>>(AGG0, AGG1, x1, x2,
      c1_Wl, c2_Wl, c1_Wr, c2_Wr, c1_bl, c2_bl, H0, H1);

  // sage2 (shared co weights): co = mish(sage(h))
  agg_mean<<<dim3(1024, 2), 256, 0, stream>>>(rp0, rp1, csr0, csr1, H0, H1, AGG0, AGG1);
  gemm128<1, 1><<<dim3(128, 2), 256, 0, stream>>>(AGG0, AGG1, H0, H1,
      co_Wl, co_Wl, co_Wr, co_Wr, co_bl, co_bl, CO0, CO1);

  // z = h + co (in place into H)
  add_kernel<<<dim3(1024, 2), 256, 0, stream>>>(H0, H1, CO0, CO1);

  // sage3: h_final = mish(sage(z)) -> CO
  agg_mean<<<dim3(1024, 2), 256, 0, stream>>>(rp0, rp1, csr0, csr1, H0, H1, AGG0, AGG1);
  gemm128<1, 1><<<dim3(128, 2), 256, 0, stream>>>(AGG0, AGG1, H0, H1,
      c3_Wl, c4_Wl, c3_Wr, c4_Wr, c3_bl, c4_bl, CO0, CO1);

  // dmon MLP: t = h@W1+b1 (AGG reused as tmp), s = softmax(t@W2+b2)
  gemm128<0, 0><<<dim3(128, 2), 256, 0, stream>>>(CO0, CO1, nullptr, nullptr,
      m_W1, m_W1, nullptr, nullptr, m_b1, m_b1, AGG0, AGG1);
  gemm128<0, 2><<<dim3(128, 2), 256, 0, stream>>>(AGG0, AGG1, nullptr, nullptr,
      m_W2, m_W2, nullptr, nullptr, m_b2, m_b2, S0, S1);

  // pooled = s^T h ; ss = s^T s  (split-K outer product, 4 quads x 16 splits)
  pool_kernel<<<dim3(4 * PK_NSPLIT, 2, 2), 256, 0, stream>>>(S0, S1, CO0, CO1,
      pooled0, pooled1, ss0, ss1);
  colca_kernel<<<dim3(64, 2), 128, 0, stream>>>(S0, S1, deg0, deg1, col0, col1, ca0, ca1);
  trace_kernel<<<dim3(256, 2), 256, 0, stream>>>(e1, e2, S0, S1, tr0, tr1);

  finalize_kernel<<<2, 256, 0, stream>>>(ss0, ss1, col0, col1, ca0, ca1, tr0, tr1,
      out + 32768);
  selu_kernel<<<dim3(64, 2), 256, 0, stream>>>(pooled0, pooled1, out);
}

// Round 4
// 396.169 us; speedup vs baseline: 2.0366x; 1.3212x over previous
//
#include <hip/hip_runtime.h>
#include <hip/hip_bf16.h>
#include <math.h>

#define NN 8192
#define DD 128
#define KK 128
#define EE 262144

typedef unsigned short ushort_t;
typedef __attribute__((ext_vector_type(8))) unsigned short us8;

__device__ __forceinline__ float b2f(ushort_t u){
  return __uint_as_float(((unsigned)u) << 16);
}
__device__ __forceinline__ ushort_t f2b(float f){
  unsigned u = __float_as_uint(f);
  unsigned r = (u + 0x7FFF + ((u >> 16) & 1)) >> 16;   // RNE
  return (ushort_t)r;
}

// ---------------------------------------------------------------- activation
__device__ __forceinline__ float mishf(float v){
  float e  = __expf(v);
  float t2 = e * (e + 2.f);
  float r  = v * (t2 / (t2 + 2.f));
  return (v > 30.f) ? v : r;
}

// ---------------------------------------------------------------- cast x -> bf16
__global__ __launch_bounds__(256) void cast_kernel(
    const float* __restrict__ x0, const float* __restrict__ x1,
    ushort_t* __restrict__ f0, ushort_t* __restrict__ f1){
  int g = blockIdx.y;
  const float* x = g ? x1 : x0;
  ushort_t* f = g ? f1 : f0;
  int idx = blockIdx.x * 256 + threadIdx.x;      // 8 floats per thread, 512 blocks
  const float4* p = (const float4*)&x[idx * 8];
  float4 a = p[0], b = p[1];
  us8 o;
  o[0] = f2b(a.x); o[1] = f2b(a.y); o[2] = f2b(a.z); o[3] = f2b(a.w);
  o[4] = f2b(b.x); o[5] = f2b(b.y); o[6] = f2b(b.z); o[7] = f2b(b.w);
  *(us8*)&f[idx * 8] = o;
}

// ---------------------------------------------------------------- CSR build
__global__ __launch_bounds__(256) void count_kernel(
    const int* __restrict__ eA, const int* __restrict__ eB,
    int* cntA, int* degA, int* cntB, int* degB){
  int g = blockIdx.y;
  const int* e  = g ? eB : eA;
  int* cnt = g ? cntB : cntA;
  int* deg = g ? degB : degA;
  const int* src = e;
  const int* dst = e + EE;
  int stride = gridDim.x * blockDim.x;
  for (int i = blockIdx.x * blockDim.x + threadIdx.x; i < EE; i += stride){
    atomicAdd(&cnt[dst[i]], 1);
    atomicAdd(&deg[src[i]], 1);
  }
}

__global__ __launch_bounds__(1024) void scan_kernel(
    const int* cntA, const int* cntB, int* rpA, int* rpB, int* curA, int* curB){
  int g = blockIdx.x;
  const int* cnt = g ? cntB : cntA;
  int* rp  = g ? rpB : rpA;
  int* cur = g ? curB : curA;
  __shared__ int sums[1024];
  int t = threadIdx.x;
  int v[8];
  int base = t * 8;
  int tot = 0;
#pragma unroll
  for (int j = 0; j < 8; ++j){ v[j] = cnt[base + j]; tot += v[j]; }
  sums[t] = tot; __syncthreads();
  for (int off = 1; off < 1024; off <<= 1){
    int x = 0;
    if (t >= off) x = sums[t - off];
    __syncthreads();
    sums[t] += x;
    __syncthreads();
  }
  int run = (t == 0) ? 0 : sums[t - 1];
#pragma unroll
  for (int j = 0; j < 8; ++j){ rp[base + j] = run; cur[base + j] = run; run += v[j]; }
  if (t == 1023) rp[NN] = run;
}

__global__ __launch_bounds__(256) void fill_csr(
    const int* __restrict__ eA, const int* __restrict__ eB,
    int* curA, int* curB, int* csrA, int* csrB){
  int g = blockIdx.y;
  const int* e = g ? eB : eA;
  int* cur = g ? curB : curA;
  int* csr = g ? csrB : csrA;
  const int* src = e;
  const int* dst = e + EE;
  int stride = gridDim.x * blockDim.x;
  for (int i = blockIdx.x * blockDim.x + threadIdx.x; i < EE; i += stride){
    int pos = atomicAdd(&cur[dst[i]], 1);
    csr[pos] = src[i];
  }
}

// ---------------------------------------------------------------- mean-aggregate (bf16 gather)
__global__ __launch_bounds__(256) void agg_mean(
    const int* __restrict__ rpA, const int* __restrict__ rpB,
    const int* __restrict__ csrA, const int* __restrict__ csrB,
    const ushort_t* __restrict__ FA, const ushort_t* __restrict__ FBp,
    float* __restrict__ MA, float* __restrict__ MB){
  int g = blockIdx.y;
  const int* rp  = g ? rpB  : rpA;
  const int* csr = g ? csrB : csrA;
  const ushort_t* F = g ? FBp : FA;
  float* M = g ? MB : MA;
  int t = threadIdx.x;
  int node = blockIdx.x * 16 + (t >> 4);
  int lane = t & 15;                      // 16 lanes x 8 elems = 128
  int beg = rp[node], end = rp[node + 1];
  float a[8];
#pragma unroll
  for (int k = 0; k < 8; ++k) a[k] = 0.f;
  for (int j = beg; j < end; ++j){
    int s = csr[j];
    us8 v = *(const us8*)&F[s * DD + lane * 8];
#pragma unroll
    for (int k = 0; k < 8; ++k) a[k] += b2f(v[k]);
  }
  float inv = 1.f / fmaxf((float)(end - beg), 1.f);
  float4 o0 = make_float4(a[0] * inv, a[1] * inv, a[2] * inv, a[3] * inv);
  float4 o1 = make_float4(a[4] * inv, a[5] * inv, a[6] * inv, a[7] * inv);
  *(float4*)&M[node * DD + lane * 8]     = o0;
  *(float4*)&M[node * DD + lane * 8 + 4] = o1;
}

// ---------------------------------------------------------------- GEMM [N,128]@[128,128]
// out = A@Wa (+ B@Wb) + bias, ACT: 0 none, 1 mish, 2 row-softmax; BF: also write bf16 copy
template<int DUAL, int ACT, int BF>
__global__ __launch_bounds__(256) void gemm128(
    const float* __restrict__ A0, const float* __restrict__ A1,
    const float* __restrict__ B0, const float* __restrict__ B1,
    const float* __restrict__ Wa0, const float* __restrict__ Wa1,
    const float* __restrict__ Wb0, const float* __restrict__ Wb1,
    const float* __restrict__ bi0, const float* __restrict__ bi1,
    float* __restrict__ O0, float* __restrict__ O1,
    ushort_t* __restrict__ OB0, ushort_t* __restrict__ OB1){
  int g = blockIdx.y;
  const float* A  = g ? A1 : A0;
  const float* B  = g ? B1 : B0;
  const float* Wa = g ? Wa1 : Wa0;
  const float* Wb = g ? Wb1 : Wb0;
  const float* bi = g ? bi1 : bi0;
  float* O = g ? O1 : O0;
  ushort_t* OB = g ? OB1 : OB0;

  __shared__ float As[64][36];
  __shared__ float Bs[DUAL ? 64 : 1][36];
  __shared__ float Was[32][132];
  __shared__ float Wbs[DUAL ? 32 : 1][132];

  int t = threadIdx.x;
  int tx = t & 15, ty = t >> 4;
  int rowBase = blockIdx.x * 64;

  float acc[4][8];
#pragma unroll
  for (int r = 0; r < 4; ++r)
#pragma unroll
    for (int c = 0; c < 8; ++c) acc[r][c] = 0.f;

  for (int kt = 0; kt < 128; kt += 32){
#pragma unroll
    for (int i = 0; i < 2; ++i){
      int idx = t * 2 + i;
      int r = idx >> 3, f = (idx & 7) * 4;
      *(float4*)&As[r][f] = *(const float4*)&A[(rowBase + r) * 128 + kt + f];
      if (DUAL) *(float4*)&Bs[r][f] = *(const float4*)&B[(rowBase + r) * 128 + kt + f];
    }
#pragma unroll
    for (int i = 0; i < 4; ++i){
      int idx = t * 4 + i;
      int r = idx >> 5, f = (idx & 31) * 4;
      *(float4*)&Was[r][f] = *(const float4*)&Wa[(kt + r) * 128 + f];
      if (DUAL) *(float4*)&Wbs[r][f] = *(const float4*)&Wb[(kt + r) * 128 + f];
    }
    __syncthreads();
#pragma unroll
    for (int kk = 0; kk < 32; ++kk){
      float wa[8], wb[8];
      *(float4*)&wa[0] = *(float4*)&Was[kk][tx * 8];
      *(float4*)&wa[4] = *(float4*)&Was[kk][tx * 8 + 4];
      if (DUAL){
        *(float4*)&wb[0] = *(float4*)&Wbs[kk][tx * 8];
        *(float4*)&wb[4] = *(float4*)&Wbs[kk][tx * 8 + 4];
      }
#pragma unroll
      for (int r = 0; r < 4; ++r){
        float a = As[ty * 4 + r][kk];
#pragma unroll
        for (int c = 0; c < 8; ++c) acc[r][c] += a * wa[c];
        if (DUAL){
          float b = Bs[ty * 4 + r][kk];
#pragma unroll
          for (int c = 0; c < 8; ++c) acc[r][c] += b * wb[c];
        }
      }
    }
    __syncthreads();
  }

  int colBase = tx * 8;
  float bv[8];
  *(float4*)&bv[0] = *(const float4*)&bi[colBase];
  *(float4*)&bv[4] = *(const float4*)&bi[colBase + 4];

#pragma unroll
  for (int r = 0; r < 4; ++r){
    float v[8];
#pragma unroll
    for (int c = 0; c < 8; ++c) v[c] = acc[r][c] + bv[c];
    if (ACT == 1){
#pragma unroll
      for (int c = 0; c < 8; ++c) v[c] = mishf(v[c]);
    }
    if (ACT == 2){
      float m = v[0];
#pragma unroll
      for (int c = 1; c < 8; ++c) m = fmaxf(m, v[c]);
      for (int msk = 1; msk < 16; msk <<= 1) m = fmaxf(m, __shfl_xor(m, msk));
      float sum = 0.f;
#pragma unroll
      for (int c = 0; c < 8; ++c){ v[c] = __expf(v[c] - m); sum += v[c]; }
      for (int msk = 1; msk < 16; msk <<= 1) sum += __shfl_xor(sum, msk);
      float inv = 1.f / sum;
#pragma unroll
      for (int c = 0; c < 8; ++c) v[c] *= inv;
    }
    int row = rowBase + ty * 4 + r;
    *(float4*)&O[row * 128 + colBase]     = make_float4(v[0], v[1], v[2], v[3]);
    *(float4*)&O[row * 128 + colBase + 4] = make_float4(v[4], v[5], v[6], v[7]);
    if (BF){
      us8 ob;
#pragma unroll
      for (int c = 0; c < 8; ++c) ob[c] = f2b(v[c]);
      *(us8*)&OB[row * 128 + colBase] = ob;
    }
  }
}

// ---------------------------------------------------------------- add (H += CO) + bf16 copy
__global__ __launch_bounds__(256) void add_kernel(
    float* HA, float* HB, const float* CA, const float* CB,
    ushort_t* FA, ushort_t* FBp){
  int g = blockIdx.y;
  float* H = g ? HB : HA;
  const float* C = g ? CB : CA;
  ushort_t* F = g ? FBp : FA;
  int idx = blockIdx.x * 256 + threadIdx.x;   // 8 floats per thread, 512 blocks
  float4 h0 = *(float4*)&H[idx * 8],     h1 = *(float4*)&H[idx * 8 + 4];
  float4 c0 = *(const float4*)&C[idx * 8], c1 = *(const float4*)&C[idx * 8 + 4];
  h0.x += c0.x; h0.y += c0.y; h0.z += c0.z; h0.w += c0.w;
  h1.x += c1.x; h1.y += c1.y; h1.z += c1.z; h1.w += c1.w;
  *(float4*)&H[idx * 8]     = h0;
  *(float4*)&H[idx * 8 + 4] = h1;
  us8 f;
  f[0] = f2b(h0.x); f[1] = f2b(h0.y); f[2] = f2b(h0.z); f[3] = f2b(h0.w);
  f[4] = f2b(h1.x); f[5] = f2b(h1.y); f[6] = f2b(h1.z); f[7] = f2b(h1.w);
  *(us8*)&F[idx * 8] = f;
}

// ---------------------------------------------------------------- pooled / ss outer products
#define PK_NSPLIT 16
__global__ __launch_bounds__(256) void pool_kernel(
    const float* __restrict__ S0, const float* __restrict__ S1,
    const float* __restrict__ H0, const float* __restrict__ H1,
    float* P0, float* P1, float* SS0, float* SS1){
  int g = blockIdx.y, z = blockIdx.z;
  const float* S = g ? S1 : S0;
  const float* Q = z ? S : (g ? H1 : H0);
  float* OUT = z ? (g ? SS1 : SS0) : (g ? P1 : P0);

  int quad  = blockIdx.x & 3;
  int split = blockIdx.x >> 2;
  int k0 = (quad >> 1) * 64;
  int d0 = (quad & 1) * 64;

  __shared__ float St[64][33];
  __shared__ float Qs[32][68];

  int t = threadIdx.x;
  int tx = t & 15, ty = t >> 4;

  float acc[4][4];
#pragma unroll
  for (int r = 0; r < 4; ++r)
#pragma unroll
    for (int c = 0; c < 4; ++c) acc[r][c] = 0.f;

  int i0base = split * (NN / PK_NSPLIT);
  for (int chunk = 0; chunk < (NN / PK_NSPLIT) / 32; ++chunk){
    int i0 = i0base + chunk * 32;
    __syncthreads();
#pragma unroll
    for (int j = 0; j < 2; ++j){
      int idx = t + j * 256;
      int row = idx >> 4, f4 = (idx & 15) * 4;
      float4 sv = *(const float4*)&S[(i0 + row) * 128 + k0 + f4];
      St[f4 + 0][row] = sv.x;
      St[f4 + 1][row] = sv.y;
      St[f4 + 2][row] = sv.z;
      St[f4 + 3][row] = sv.w;
      *(float4*)&Qs[row][f4] = *(const float4*)&Q[(i0 + row) * 128 + d0 + f4];
    }
    __syncthreads();
#pragma unroll 8
    for (int i = 0; i < 32; ++i){
      float4 qv = *(float4*)&Qs[i][tx * 4];
      float s0 = St[ty * 4 + 0][i];
      float s1 = St[ty * 4 + 1][i];
      float s2 = St[ty * 4 + 2][i];
      float s3 = St[ty * 4 + 3][i];
      acc[0][0] += s0 * qv.x; acc[0][1] += s0 * qv.y; acc[0][2] += s0 * qv.z; acc[0][3] += s0 * qv.w;
      acc[1][0] += s1 * qv.x; acc[1][1] += s1 * qv.y; acc[1][2] += s1 * qv.z; acc[1][3] += s1 * qv.w;
      acc[2][0] += s2 * qv.x; acc[2][1] += s2 * qv.y; acc[2][2] += s2 * qv.z; acc[2][3] += s2 * qv.w;
      acc[3][0] += s3 * qv.x; acc[3][1] += s3 * qv.y; acc[3][2] += s3 * qv.z; acc[3][3] += s3 * qv.w;
    }
  }

  int k = k0 + ty * 4, d = d0 + tx * 4;
#pragma unroll
  for (int r = 0; r < 4; ++r)
#pragma unroll
    for (int c = 0; c < 4; ++c)
      atomicAdd(&OUT[(k + r) * 128 + d + c], acc[r][c]);
}

// ---------------------------------------------------------------- colsum + ca
__global__ __launch_bounds__(128) void colca_kernel(
    const float* S0, const float* S1, const int* dg0, const int* dg1,
    float* col0, float* col1, float* ca0, float* ca1){
  int g = blockIdx.y;
  const float* S = g ? S1 : S0;
  const int* dg = g ? dg1 : dg0;
  float* col = g ? col1 : col0;
  float* ca  = g ? ca1  : ca0;
  int k = threadIdx.x;
  int i0 = blockIdx.x * 128;
  float cs = 0.f, cc = 0.f;
  for (int i = i0; i < i0 + 128; ++i){
    float v = S[i * 128 + k];
    cs += v;
    cc += v * (float)dg[i];
  }
  atomicAdd(&col[k], cs);
  atomicAdd(&ca[k], cc);
}

// ---------------------------------------------------------------- trace(s^T adj s) via CSR, bf16
__global__ __launch_bounds__(256) void trace_kernel(
    const int* __restrict__ rpA, const int* __restrict__ rpB,
    const int* __restrict__ csrA, const int* __restrict__ csrB,
    const ushort_t* __restrict__ SA, const ushort_t* __restrict__ SBp,
    float* tr0, float* tr1){
  int g = blockIdx.y;
  const int* rp  = g ? rpB  : rpA;
  const int* csr = g ? csrB : csrA;
  const ushort_t* S = g ? SBp : SA;
  float* tr = g ? tr1 : tr0;
  int t = threadIdx.x;
  int grp = t >> 4, lane = t & 15;
  int node = blockIdx.x * 16 + grp;
  int beg = rp[node], end = rp[node + 1];
  // own (dst) row slice in registers
  us8 w = *(const us8*)&S[node * DD + lane * 8];
  float o[8];
#pragma unroll
  for (int k = 0; k < 8; ++k) o[k] = b2f(w[k]);
  float acc = 0.f;
  for (int j = beg; j < end; ++j){
    int s = csr[j];
    us8 v = *(const us8*)&S[s * DD + lane * 8];
#pragma unroll
    for (int k = 0; k < 8; ++k) acc += o[k] * b2f(v[k]);
  }
  for (int m = 1; m < 16; m <<= 1) acc += __shfl_xor(acc, m);
  __shared__ float part[16];
  if (lane == 0) part[grp] = acc;
  __syncthreads();
  if (t == 0){
    float s = 0.f;
#pragma unroll
    for (int i = 0; i < 16; ++i) s += part[i];
    atomicAdd(tr, s);
  }
}

// ---------------------------------------------------------------- losses
__device__ float block_reduce(float v, float* red, int t){
  red[t] = v; __syncthreads();
  for (int o = 128; o > 0; o >>= 1){
    if (t < o) red[t] += red[t + o];
    __syncthreads();
  }
  float r = red[0]; __syncthreads();
  return r;
}

__global__ __launch_bounds__(256) void finalize_kernel(
    const float* ss0, const float* ss1, const float* col0, const float* col1,
    const float* ca0, const float* ca1, const float* tr0, const float* tr1,
    float* loss_out){
  int g = blockIdx.x;
  const float* ss  = g ? ss1  : ss0;
  const float* col = g ? col1 : col0;
  const float* ca  = g ? ca1  : ca0;
  const float* tr  = g ? tr1  : tr0;
  __shared__ float red[256];
  int t = threadIdx.x;
  float s2 = 0.f;
  for (int i = t; i < 16384; i += 256){ float x = ss[i]; s2 += x * x; }
  float F2   = block_reduce(s2, red, t);
  float trss = block_reduce((t < 128) ? ss[t * 129] : 0.f, red, t);
  float ca2  = block_reduce((t < 128) ? ca[t] * ca[t] : 0.f, red, t);
  float cs2  = block_reduce((t < 128) ? col[t] * col[t] : 0.f, red, t);
  if (t == 0){
    float F = sqrtf(F2);
    float ortho = sqrtf(fmaxf(2.f - 2.f * trss / (F * sqrtf((float)KK)), 0.f));
    float m2 = (float)EE;                 // 2m
    float spectral = -(tr[0] - ca2 / m2) / m2;
    float cluster = sqrtf(cs2) / (float)NN * sqrtf((float)KK) - 1.f;
    atomicAdd(loss_out, spectral + ortho + cluster);
  }
}

// ---------------------------------------------------------------- selu + store pooled
__global__ __launch_bounds__(256) void selu_kernel(
    const float* p0, const float* p1, float* out){
  int g = blockIdx.y;
  const float* p = g ? p1 : p0;
  int idx = blockIdx.x * 256 + threadIdx.x;
  float v = p[idx];
  const float scale = 1.0507009873554805f, alpha = 1.6732632423543772f;
  float r = (v > 0.f) ? scale * v : scale * alpha * expm1f(v);
  out[g * 16384 + idx] = r;
}

// ---------------------------------------------------------------- launch
extern "C" void kernel_launch(void* const* d_in, const int* in_sizes, int n_in,
                              void* d_out, int out_size, void* d_ws, size_t ws_size,
                              hipStream_t stream){
  const float* x1 = (const float*)d_in[0];
  const float* x2 = (const float*)d_in[1];
  const int*   e1 = (const int*)d_in[2];
  const int*   e2 = (const int*)d_in[3];
  const float* c1_Wl = (const float*)d_in[4];
  const float* c1_bl = (const float*)d_in[5];
  const float* c1_Wr = (const float*)d_in[6];
  const float* c2_Wl = (const float*)d_in[7];
  const float* c2_bl = (const float*)d_in[8];
  const float* c2_Wr = (const float*)d_in[9];
  const float* co_Wl = (const float*)d_in[10];
  const float* co_bl = (const float*)d_in[11];
  const float* co_Wr = (const float*)d_in[12];
  const float* c3_Wl = (const float*)d_in[13];
  const float* c3_bl = (const float*)d_in[14];
  const float* c3_Wr = (const float*)d_in[15];
  const float* c4_Wl = (const float*)d_in[16];
  const float* c4_bl = (const float*)d_in[17];
  const float* c4_Wr = (const float*)d_in[18];
  const float* m_W1 = (const float*)d_in[19];
  const float* m_b1 = (const float*)d_in[20];
  const float* m_W2 = (const float*)d_in[21];
  const float* m_b2 = (const float*)d_in[22];
  float* out = (float*)d_out;

  char* w = (char*)d_ws;
  auto alloc = [&](size_t bytes) -> char* {
    char* p = w;
    w += (bytes + 255) / 256 * 256;
    return p;
  };
  // zero region A: counts
  int* cnt0 = (int*)alloc(NN * 4);
  int* deg0 = (int*)alloc(NN * 4);
  int* cnt1 = (int*)alloc(NN * 4);
  int* deg1 = (int*)alloc(NN * 4);
  size_t zeroA_len = (size_t)(w - (char*)cnt0);
  // zero region B: accumulators
  float* pooled0 = (float*)alloc(16384 * 4);
  float* ss0     = (float*)alloc(16384 * 4);
  float* col0    = (float*)alloc(128 * 4);
  float* ca0     = (float*)alloc(128 * 4);
  float* tr0     = (float*)alloc(256);
  float* pooled1 = (float*)alloc(16384 * 4);
  float* ss1     = (float*)alloc(16384 * 4);
  float* col1    = (float*)alloc(128 * 4);
  float* ca1     = (float*)alloc(128 * 4);
  float* tr1     = (float*)alloc(256);
  size_t zeroB_len = (size_t)(w - (char*)pooled0);
  // CSR
  int* rp0  = (int*)alloc((NN + 1) * 4);
  int* cur0 = (int*)alloc(NN * 4);
  int* csr0 = (int*)alloc(EE * 4);
  int* rp1  = (int*)alloc((NN + 1) * 4);
  int* cur1 = (int*)alloc(NN * 4);
  int* csr1 = (int*)alloc(EE * 4);
  // feature buffers
  float* H0   = (float*)alloc((size_t)NN * DD * 4);
  float* AGG0 = (float*)alloc((size_t)NN * DD * 4);
  float* CO0  = (float*)alloc((size_t)NN * DD * 4);
  float* S0   = (float*)alloc((size_t)NN * DD * 4);
  float* H1   = (float*)alloc((size_t)NN * DD * 4);
  float* AGG1 = (float*)alloc((size_t)NN * DD * 4);
  float* CO1  = (float*)alloc((size_t)NN * DD * 4);
  float* S1   = (float*)alloc((size_t)NN * DD * 4);

  // bf16 aliases (no extra workspace):
  //  - FBF: current features for agg gathers; lives in S0/S1 space (S f32 written later)
  //  - SBF: softmax bf16 for trace; lives in H0/H1 space (H dead after last agg/gemm)
  ushort_t* FBF0 = (ushort_t*)S0;
  ushort_t* FBF1 = (ushort_t*)S1;
  ushort_t* SBF0 = (ushort_t*)H0;
  ushort_t* SBF1 = (ushort_t*)H1;

  hipMemsetAsync(cnt0, 0, zeroA_len, stream);
  hipMemsetAsync(pooled0, 0, zeroB_len, stream);
  hipMemsetAsync(out + 32768, 0, 4, stream);

  // CSR build (both graphs)
  count_kernel<<<dim3(256, 2), 256, 0, stream>>>(e1, e2, cnt0, deg0, cnt1, deg1);
  scan_kernel<<<2, 1024, 0, stream>>>(cnt0, cnt1, rp0, rp1, cur0, cur1);
  fill_csr<<<dim3(256, 2), 256, 0, stream>>>(e1, e2, cur0, cur1, csr0, csr1);

  // bf16 cast of inputs (512 blocks x 256 thr x 8 elems = N*D)
  cast_kernel<<<dim3(512, 2), 256, 0, stream>>>(x1, x2, FBF0, FBF1);

  // sage1: h = mish(mean@Wl + x@Wr + bl); also emit h in bf16 -> FBF
  agg_mean<<<dim3(512, 2), 256, 0, stream>>>(rp0, rp1, csr0, csr1, FBF0, FBF1, AGG0, AGG1);
  gemm128<1, 1, 1><<<dim3(128, 2), 256, 0, stream>>>(AGG0, AGG1, x1, x2,
      c1_Wl, c2_Wl, c1_Wr, c2_Wr, c1_bl, c2_bl, H0, H1, FBF0, FBF1);

  // sage2 (shared co weights): co = mish(sage(h))
  agg_mean<<<dim3(512, 2), 256, 0, stream>>>(rp0, rp1, csr0, csr1, FBF0, FBF1, AGG0, AGG1);
  gemm128<1, 1, 0><<<dim3(128, 2), 256, 0, stream>>>(AGG0, AGG1, H0, H1,
      co_Wl, co_Wl, co_Wr, co_Wr, co_bl, co_bl, CO0, CO1, nullptr, nullptr);

  // z = h + co (in place into H) + bf16 -> FBF (512 blocks)
  add_kernel<<<dim3(512, 2), 256, 0, stream>>>(H0, H1, CO0, CO1, FBF0, FBF1);

  // sage3: h_final = mish(sage(z)) -> CO
  agg_mean<<<dim3(512, 2), 256, 0, stream>>>(rp0, rp1, csr0, csr1, FBF0, FBF1, AGG0, AGG1);
  gemm128<1, 1, 0><<<dim3(128, 2), 256, 0, stream>>>(AGG0, AGG1, H0, H1,
      c3_Wl, c4_Wl, c3_Wr, c4_Wr, c3_bl, c4_bl, CO0, CO1, nullptr, nullptr);

  // dmon MLP: t = h@W1+b1 (AGG reused as tmp), s = softmax(t@W2+b2) (+ bf16 -> SBF)
  gemm128<0, 0, 0><<<dim3(128, 2), 256, 0, stream>>>(CO0, CO1, nullptr, nullptr,
      m_W1, m_W1, nullptr, nullptr, m_b1, m_b1, AGG0, AGG1, nullptr, nullptr);
  gemm128<0, 2, 1><<<dim3(128, 2), 256, 0, stream>>>(AGG0, AGG1, nullptr, nullptr,
      m_W2, m_W2, nullptr, nullptr, m_b2, m_b2, S0, S1, SBF0, SBF1);

  // pooled = s^T h ; ss = s^T s  (split-K outer product)
  pool_kernel<<<dim3(4 * PK_NSPLIT, 2, 2), 256, 0, stream>>>(S0, S1, CO0, CO1,
      pooled0, pooled1, ss0, ss1);
  colca_kernel<<<dim3(64, 2), 128, 0, stream>>>(S0, S1, deg0, deg1, col0, col1, ca0, ca1);
  trace_kernel<<<dim3(512, 2), 256, 0, stream>>>(rp0, rp1, csr0, csr1, SBF0, SBF1, tr0, tr1);

  finalize_kernel<<<2, 256, 0, stream>>>(ss0, ss1, col0, col1, ca0, ca1, tr0, tr1,
      out + 32768);
  selu_kernel<<<dim3(64, 2), 256, 0, stream>>>(pooled0, pooled1, out);
}

// Round 5
// 348.348 us; speedup vs baseline: 2.3161x; 1.1373x over previous
//
#include <hip/hip_runtime.h>
#include <math.h>

#define NN 8192
#define DD 128
#define KK 128
#define EE 262144

typedef _Float16 f16;
typedef __attribute__((ext_vector_type(8))) _Float16 f16x8;
typedef __attribute__((ext_vector_type(4))) float f32x4;

// ---------------------------------------------------------------- activation
__device__ __forceinline__ float mishf(float v){
  float e  = __expf(v);
  float t2 = e * (e + 2.f);
  float r  = v * (t2 / (t2 + 2.f));
  return (v > 30.f) ? v : r;
}

// ---------------------------------------------------------------- cast x -> fp16
__global__ __launch_bounds__(256) void cast_kernel(
    const float* __restrict__ x0, const float* __restrict__ x1,
    f16* __restrict__ f0, f16* __restrict__ f1){
  int g = blockIdx.y;
  const float* x = g ? x1 : x0;
  f16* f = g ? f1 : f0;
  int idx = blockIdx.x * 256 + threadIdx.x;      // 8 floats/thread, 512 blocks
  const float4* p = (const float4*)&x[idx * 8];
  float4 a = p[0], b = p[1];
  f16x8 o;
  o[0] = (f16)a.x; o[1] = (f16)a.y; o[2] = (f16)a.z; o[3] = (f16)a.w;
  o[4] = (f16)b.x; o[5] = (f16)b.y; o[6] = (f16)b.z; o[7] = (f16)b.w;
  *(f16x8*)&f[idx * 8] = o;
}

// ---------------------------------------------------------------- weight prep: cast+transpose
__global__ __launch_bounds__(256) void wprep(
    const float* w0, const float* w1, const float* w2, const float* w3,
    const float* w4, const float* w5, const float* w6, const float* w7,
    const float* w8, const float* w9, const float* w10, const float* w11,
    f16* WT){
  const float* Ws[12] = {w0,w1,w2,w3,w4,w5,w6,w7,w8,w9,w10,w11};
  const float* W = Ws[blockIdx.x];
  f16* O = WT + (size_t)blockIdx.x * 16384;
  int t = threadIdx.x;
  int n = t >> 1, k0 = (t & 1) * 64;
  for (int k = 0; k < 64; ++k)
    O[n * 128 + k0 + k] = (f16)W[(k0 + k) * 128 + n];
}

// ---------------------------------------------------------------- CSR build
__global__ __launch_bounds__(256) void count_kernel(
    const int* __restrict__ eA, const int* __restrict__ eB,
    int* cntA, int* degA, int* cntB, int* degB){
  int g = blockIdx.y;
  const int* e  = g ? eB : eA;
  int* cnt = g ? cntB : cntA;
  int* deg = g ? degB : degA;
  const int* src = e;
  const int* dst = e + EE;
  int stride = gridDim.x * blockDim.x;
  for (int i = blockIdx.x * blockDim.x + threadIdx.x; i < EE; i += stride){
    atomicAdd(&cnt[dst[i]], 1);
    atomicAdd(&deg[src[i]], 1);
  }
}

__global__ __launch_bounds__(1024) void scan_kernel(
    const int* cntA, const int* cntB, int* rpA, int* rpB, int* curA, int* curB){
  int g = blockIdx.x;
  const int* cnt = g ? cntB : cntA;
  int* rp  = g ? rpB : rpA;
  int* cur = g ? curB : curA;
  __shared__ int sums[1024];
  int t = threadIdx.x;
  int v[8];
  int base = t * 8;
  int tot = 0;
#pragma unroll
  for (int j = 0; j < 8; ++j){ v[j] = cnt[base + j]; tot += v[j]; }
  sums[t] = tot; __syncthreads();
  for (int off = 1; off < 1024; off <<= 1){
    int x = 0;
    if (t >= off) x = sums[t - off];
    __syncthreads();
    sums[t] += x;
    __syncthreads();
  }
  int run = (t == 0) ? 0 : sums[t - 1];
#pragma unroll
  for (int j = 0; j < 8; ++j){ rp[base + j] = run; cur[base + j] = run; run += v[j]; }
  if (t == 1023) rp[NN] = run;
}

__global__ __launch_bounds__(256) void fill_csr(
    const int* __restrict__ eA, const int* __restrict__ eB,
    int* curA, int* curB, int* csrA, int* csrB){
  int g = blockIdx.y;
  const int* e = g ? eB : eA;
  int* cur = g ? curB : curA;
  int* csr = g ? csrB : csrA;
  const int* src = e;
  const int* dst = e + EE;
  int stride = gridDim.x * blockDim.x;
  for (int i = blockIdx.x * blockDim.x + threadIdx.x; i < EE; i += stride){
    int pos = atomicAdd(&cur[dst[i]], 1);
    csr[pos] = src[i];
  }
}

// ---------------------------------------------------------------- mean-aggregate (fp16 gather)
__global__ __launch_bounds__(256) void agg_mean(
    const int* __restrict__ rpA, const int* __restrict__ rpB,
    const int* __restrict__ csrA, const int* __restrict__ csrB,
    const f16* __restrict__ FA, const f16* __restrict__ FBp,
    f16* __restrict__ MA, f16* __restrict__ MB){
  int g = blockIdx.y;
  const int* rp  = g ? rpB  : rpA;
  const int* csr = g ? csrB : csrA;
  const f16* F = g ? FBp : FA;
  f16* M = g ? MB : MA;
  int t = threadIdx.x;
  int node = blockIdx.x * 16 + (t >> 4);
  int lane = t & 15;                      // 16 lanes x 8 elems = 128
  int beg = rp[node], end = rp[node + 1];
  float a[8];
#pragma unroll
  for (int k = 0; k < 8; ++k) a[k] = 0.f;
  for (int j = beg; j < end; ++j){
    int s = csr[j];
    f16x8 v = *(const f16x8*)&F[s * DD + lane * 8];
#pragma unroll
    for (int k = 0; k < 8; ++k) a[k] += (float)v[k];
  }
  float inv = 1.f / fmaxf((float)(end - beg), 1.f);
  f16x8 o;
#pragma unroll
  for (int k = 0; k < 8; ++k) o[k] = (f16)(a[k] * inv);
  *(f16x8*)&M[node * DD + lane * 8] = o;
}

// ---------------------------------------------------------------- MFMA GEMM [8192,128]@[128,128]
// O = ACT(A@Wa (+ B@Wb) + bias) (+ ADD for FUSEADD). W given transposed [n][k] fp16.
// Block: 128 thr = 2 waves; 64 rows/block (32/wave), full 128 cols, K=128.
template<int DUAL, int ACT, int FUSEADD>
__global__ __launch_bounds__(128) void gemm_mfma(
    const f16* __restrict__ A0, const f16* __restrict__ A1,
    const f16* __restrict__ B0, const f16* __restrict__ B1,
    const f16* __restrict__ WaT0, const f16* __restrict__ WaT1,
    const f16* __restrict__ WbT0, const f16* __restrict__ WbT1,
    const float* __restrict__ bi0, const float* __restrict__ bi1,
    const f16* __restrict__ ADD0, const f16* __restrict__ ADD1,
    f16* __restrict__ O0, f16* __restrict__ O1){
  int g = blockIdx.y;
  const f16* A   = g ? A1 : A0;
  const f16* B   = g ? B1 : B0;
  const f16* WaT = g ? WaT1 : WaT0;
  const f16* WbT = g ? WbT1 : WbT0;
  const float* bi = g ? bi1 : bi0;
  const f16* ADD = g ? ADD1 : ADD0;
  f16* O = g ? O1 : O0;

  int t = threadIdx.x;
  int wave = t >> 6, l = t & 63;
  int lrow = l & 15;
  int lk = (l >> 4) * 8;
  int rowBase = blockIdx.x * 64 + wave * 32;

  f32x4 acc[2][8];
#pragma unroll
  for (int rt = 0; rt < 2; ++rt)
#pragma unroll
    for (int nt = 0; nt < 8; ++nt)
      acc[rt][nt] = (f32x4){0.f, 0.f, 0.f, 0.f};

#pragma unroll
  for (int kc = 0; kc < 4; ++kc){
    int kb = kc * 32 + lk;
    f16x8 a0 = *(const f16x8*)&A[(rowBase + lrow) * 128 + kb];
    f16x8 a1 = *(const f16x8*)&A[(rowBase + 16 + lrow) * 128 + kb];
#pragma unroll
    for (int nt = 0; nt < 8; ++nt){
      f16x8 bw = *(const f16x8*)&WaT[(nt * 16 + lrow) * 128 + kb];
      acc[0][nt] = __builtin_amdgcn_mfma_f32_16x16x32_f16(a0, bw, acc[0][nt], 0, 0, 0);
      acc[1][nt] = __builtin_amdgcn_mfma_f32_16x16x32_f16(a1, bw, acc[1][nt], 0, 0, 0);
    }
    if (DUAL){
      f16x8 c0 = *(const f16x8*)&B[(rowBase + lrow) * 128 + kb];
      f16x8 c1 = *(const f16x8*)&B[(rowBase + 16 + lrow) * 128 + kb];
#pragma unroll
      for (int nt = 0; nt < 8; ++nt){
        f16x8 bw = *(const f16x8*)&WbT[(nt * 16 + lrow) * 128 + kb];
        acc[0][nt] = __builtin_amdgcn_mfma_f32_16x16x32_f16(c0, bw, acc[0][nt], 0, 0, 0);
        acc[1][nt] = __builtin_amdgcn_mfma_f32_16x16x32_f16(c1, bw, acc[1][nt], 0, 0, 0);
      }
    }
  }

  // epilogue: C/D layout col = l&15, row = (l>>4)*4 + r
  int col16 = l & 15;
  int rgrp = (l >> 4) * 4;
  float bv[8];
#pragma unroll
  for (int nt = 0; nt < 8; ++nt) bv[nt] = bi[nt * 16 + col16];

#pragma unroll
  for (int rt = 0; rt < 2; ++rt){
#pragma unroll
    for (int r = 0; r < 4; ++r){
      int row = rowBase + rt * 16 + rgrp + r;
      float v[8];
#pragma unroll
      for (int nt = 0; nt < 8; ++nt) v[nt] = acc[rt][nt][r] + bv[nt];
      if (ACT == 1){
#pragma unroll
        for (int nt = 0; nt < 8; ++nt) v[nt] = mishf(v[nt]);
      }
      if (ACT == 2){
        float m = v[0];
#pragma unroll
        for (int nt = 1; nt < 8; ++nt) m = fmaxf(m, v[nt]);
        for (int msk = 1; msk < 16; msk <<= 1) m = fmaxf(m, __shfl_xor(m, msk));
        float sum = 0.f;
#pragma unroll
        for (int nt = 0; nt < 8; ++nt){ v[nt] = __expf(v[nt] - m); sum += v[nt]; }
        for (int msk = 1; msk < 16; msk <<= 1) sum += __shfl_xor(sum, msk);
        float inv = 1.f / sum;
#pragma unroll
        for (int nt = 0; nt < 8; ++nt) v[nt] *= inv;
      }
      if (FUSEADD){
#pragma unroll
        for (int nt = 0; nt < 8; ++nt) v[nt] += (float)ADD[row * 128 + nt * 16 + col16];
      }
#pragma unroll
      for (int nt = 0; nt < 8; ++nt)
        O[row * 128 + nt * 16 + col16] = (f16)v[nt];
    }
  }
}

// ---------------------------------------------------------------- fp16 transpose [8192][128]->[128][8192]
__global__ __launch_bounds__(256) void transpose_kernel(
    const f16* __restrict__ in0A, const f16* __restrict__ in1A,   // z=0 src (S)
    const f16* __restrict__ in0B, const f16* __restrict__ in1B,   // z=1 src (Hf)
    f16* __restrict__ o0A, f16* __restrict__ o1A,
    f16* __restrict__ o0B, f16* __restrict__ o1B){
  int g = blockIdx.y, z = blockIdx.z;
  const f16* in = z ? (g ? in1B : in0B) : (g ? in1A : in0A);
  f16* outp     = z ? (g ? o1B  : o0B)  : (g ? o1A  : o0A);
  __shared__ f16 T[32][136];
  int t = threadIdx.x;
  int i0 = blockIdx.x * 32;
#pragma unroll
  for (int j = 0; j < 2; ++j){
    int idx = t + j * 256;
    int row = idx >> 4, c8 = (idx & 15) * 8;
    f16x8 v = *(const f16x8*)&in[(i0 + row) * 128 + c8];
#pragma unroll
    for (int q = 0; q < 8; ++q) T[row][c8 + q] = v[q];
  }
  __syncthreads();
  int k = t >> 1, seg = (t & 1) * 16;
  f16x8 oA, oB;
#pragma unroll
  for (int q = 0; q < 8; ++q){ oA[q] = T[seg + q][k]; oB[q] = T[seg + 8 + q][k]; }
  *(f16x8*)&outp[(size_t)k * NN + i0 + seg]     = oA;
  *(f16x8*)&outp[(size_t)k * NN + i0 + seg + 8] = oB;
}

// ---------------------------------------------------------------- pooled/ss via MFMA split-K
// OUT[r][c] = sum_i ST[r][i] * BT[c][i];  z=0: BT=HT -> pooled, z=1: BT=ST -> ss
#define PK_NSPLIT 32
__global__ __launch_bounds__(256) void pool_mfma(
    const f16* __restrict__ ST0, const f16* __restrict__ ST1,
    const f16* __restrict__ HT0, const f16* __restrict__ HT1,
    float* P0, float* P1, float* SS0, float* SS1){
  int g = blockIdx.y, z = blockIdx.z;
  const f16* A = g ? ST1 : ST0;
  const f16* B = z ? A : (g ? HT1 : HT0);
  float* OUT = z ? (g ? SS1 : SS0) : (g ? P1 : P0);

  int t = threadIdx.x;
  int wave = t >> 6, l = t & 63;
  int lrow = l & 15;
  int lk = (l >> 4) * 8;
  int krow = wave * 32;                   // output rows [krow, krow+32)
  int i0 = blockIdx.x * (NN / PK_NSPLIT); // K slab of 256

  f32x4 acc[2][8];
#pragma unroll
  for (int rt = 0; rt < 2; ++rt)
#pragma unroll
    for (int nt = 0; nt < 8; ++nt)
      acc[rt][nt] = (f32x4){0.f, 0.f, 0.f, 0.f};

#pragma unroll 2
  for (int c = 0; c < NN / PK_NSPLIT; c += 32){
    int ib = i0 + c + lk;
    f16x8 a0 = *(const f16x8*)&A[(size_t)(krow + lrow) * NN + ib];
    f16x8 a1 = *(const f16x8*)&A[(size_t)(krow + 16 + lrow) * NN + ib];
#pragma unroll
    for (int nt = 0; nt < 8; ++nt){
      f16x8 bf = *(const f16x8*)&B[(size_t)(nt * 16 + lrow) * NN + ib];
      acc[0][nt] = __builtin_amdgcn_mfma_f32_16x16x32_f16(a0, bf, acc[0][nt], 0, 0, 0);
      acc[1][nt] = __builtin_amdgcn_mfma_f32_16x16x32_f16(a1, bf, acc[1][nt], 0, 0, 0);
    }
  }

  int col = l & 15;
  int rbase = (l >> 4) * 4;
#pragma unroll
  for (int rt = 0; rt < 2; ++rt)
#pragma unroll
    for (int nt = 0; nt < 8; ++nt)
#pragma unroll
      for (int r = 0; r < 4; ++r)
        atomicAdd(&OUT[(krow + rt * 16 + rbase + r) * 128 + nt * 16 + col], acc[rt][nt][r]);
}

// ---------------------------------------------------------------- colsum + ca from ST
__global__ __launch_bounds__(256) void colca_kernel(
    const f16* __restrict__ ST0, const f16* __restrict__ ST1,
    const int* __restrict__ dg0, const int* __restrict__ dg1,
    float* col0, float* col1, float* ca0, float* ca1){
  int g = blockIdx.y;
  const f16* ST = g ? ST1 : ST0;
  const int* dg = g ? dg1 : dg0;
  float* col = g ? col1 : col0;
  float* ca  = g ? ca1  : ca0;
  int k = blockIdx.x;
  int t = threadIdx.x;
  float cs = 0.f, cc = 0.f;
  for (int i = t * 8; i < NN; i += 2048){
    f16x8 v = *(const f16x8*)&ST[(size_t)k * NN + i];
#pragma unroll
    for (int j = 0; j < 8; ++j){
      float f = (float)v[j];
      cs += f;
      cc += f * (float)dg[i + j];
    }
  }
  __shared__ float r1[256], r2[256];
  r1[t] = cs; r2[t] = cc; __syncthreads();
  for (int o = 128; o > 0; o >>= 1){
    if (t < o){ r1[t] += r1[t + o]; r2[t] += r2[t + o]; }
    __syncthreads();
  }
  if (t == 0){ col[k] = r1[0]; ca[k] = r2[0]; }
}

// ---------------------------------------------------------------- trace(s^T adj s) via CSR, fp16
__global__ __launch_bounds__(256) void trace_kernel(
    const int* __restrict__ rpA, const int* __restrict__ rpB,
    const int* __restrict__ csrA, const int* __restrict__ csrB,
    const f16* __restrict__ SA, const f16* __restrict__ SBp,
    float* tr0, float* tr1){
  int g = blockIdx.y;
  const int* rp  = g ? rpB  : rpA;
  const int* csr = g ? csrB : csrA;
  const f16* S = g ? SBp : SA;
  float* tr = g ? tr1 : tr0;
  int t = threadIdx.x;
  int grp = t >> 4, lane = t & 15;
  int node = blockIdx.x * 16 + grp;
  int beg = rp[node], end = rp[node + 1];
  f16x8 w = *(const f16x8*)&S[node * DD + lane * 8];
  float o[8];
#pragma unroll
  for (int k = 0; k < 8; ++k) o[k] = (float)w[k];
  float acc = 0.f;
  for (int j = beg; j < end; ++j){
    int s = csr[j];
    f16x8 v = *(const f16x8*)&S[s * DD + lane * 8];
#pragma unroll
    for (int k = 0; k < 8; ++k) acc += o[k] * (float)v[k];
  }
  for (int m = 1; m < 16; m <<= 1) acc += __shfl_xor(acc, m);
  __shared__ float part[16];
  if (lane == 0) part[grp] = acc;
  __syncthreads();
  if (t == 0){
    float s = 0.f;
#pragma unroll
    for (int i = 0; i < 16; ++i) s += part[i];
    atomicAdd(tr, s);
  }
}

// ---------------------------------------------------------------- losses
__device__ float block_reduce(float v, float* red, int t){
  red[t] = v; __syncthreads();
  for (int o = 128; o > 0; o >>= 1){
    if (t < o) red[t] += red[t + o];
    __syncthreads();
  }
  float r = red[0]; __syncthreads();
  return r;
}

__global__ __launch_bounds__(256) void finalize_kernel(
    const float* ss0, const float* ss1, const float* col0, const float* col1,
    const float* ca0, const float* ca1, const float* tr0, const float* tr1,
    float* loss_out){
  int g = blockIdx.x;
  const float* ss  = g ? ss1  : ss0;
  const float* col = g ? col1 : col0;
  const float* ca  = g ? ca1  : ca0;
  const float* tr  = g ? tr1  : tr0;
  __shared__ float red[256];
  int t = threadIdx.x;
  float s2 = 0.f;
  for (int i = t; i < 16384; i += 256){ float x = ss[i]; s2 += x * x; }
  float F2   = block_reduce(s2, red, t);
  float trss = block_reduce((t < 128) ? ss[t * 129] : 0.f, red, t);
  float ca2  = block_reduce((t < 128) ? ca[t] * ca[t] : 0.f, red, t);
  float cs2  = block_reduce((t < 128) ? col[t] * col[t] : 0.f, red, t);
  if (t == 0){
    float F = sqrtf(F2);
    float ortho = sqrtf(fmaxf(2.f - 2.f * trss / (F * sqrtf((float)KK)), 0.f));
    float m2 = (float)EE;                 // 2m
    float spectral = -(tr[0] - ca2 / m2) / m2;
    float cluster = sqrtf(cs2) / (float)NN * sqrtf((float)KK) - 1.f;
    atomicAdd(loss_out, spectral + ortho + cluster);
  }
}

// ---------------------------------------------------------------- selu + store pooled
__global__ __launch_bounds__(256) void selu_kernel(
    const float* p0, const float* p1, float* out){
  int g = blockIdx.y;
  const float* p = g ? p1 : p0;
  int idx = blockIdx.x * 256 + threadIdx.x;
  float v = p[idx];
  const float scale = 1.0507009873554805f, alpha = 1.6732632423543772f;
  float r = (v > 0.f) ? scale * v : scale * alpha * expm1f(v);
  out[g * 16384 + idx] = r;
}

// ---------------------------------------------------------------- launch
extern "C" void kernel_launch(void* const* d_in, const int* in_sizes, int n_in,
                              void* d_out, int out_size, void* d_ws, size_t ws_size,
                              hipStream_t stream){
  const float* x1 = (const float*)d_in[0];
  const float* x2 = (const float*)d_in[1];
  const int*   e1 = (const int*)d_in[2];
  const int*   e2 = (const int*)d_in[3];
  const float* c1_Wl = (const float*)d_in[4];
  const float* c1_bl = (const float*)d_in[5];
  const float* c1_Wr = (const float*)d_in[6];
  const float* c2_Wl = (const float*)d_in[7];
  const float* c2_bl = (const float*)d_in[8];
  const float* c2_Wr = (const float*)d_in[9];
  const float* co_Wl = (const float*)d_in[10];
  const float* co_bl = (const float*)d_in[11];
  const float* co_Wr = (const float*)d_in[12];
  const float* c3_Wl = (const float*)d_in[13];
  const float* c3_bl = (const float*)d_in[14];
  const float* c3_Wr = (const float*)d_in[15];
  const float* c4_Wl = (const float*)d_in[16];
  const float* c4_bl = (const float*)d_in[17];
  const float* c4_Wr = (const float*)d_in[18];
  const float* m_W1 = (const float*)d_in[19];
  const float* m_b1 = (const float*)d_in[20];
  const float* m_W2 = (const float*)d_in[21];
  const float* m_b2 = (const float*)d_in[22];
  float* out = (float*)d_out;

  char* w = (char*)d_ws;
  auto alloc = [&](size_t bytes) -> char* {
    char* p = w;
    w += (bytes + 255) / 256 * 256;
    return p;
  };
  // zero region A: counts
  int* cnt0 = (int*)alloc(NN * 4);
  int* deg0 = (int*)alloc(NN * 4);
  int* cnt1 = (int*)alloc(NN * 4);
  int* deg1 = (int*)alloc(NN * 4);
  size_t zeroA_len = (size_t)(w - (char*)cnt0);
  // zero region B: accumulators
  float* pooled0 = (float*)alloc(16384 * 4);
  float* ss0     = (float*)alloc(16384 * 4);
  float* col0    = (float*)alloc(128 * 4);
  float* ca0     = (float*)alloc(128 * 4);
  float* tr0     = (float*)alloc(256);
  float* pooled1 = (float*)alloc(16384 * 4);
  float* ss1     = (float*)alloc(16384 * 4);
  float* col1    = (float*)alloc(128 * 4);
  float* ca1     = (float*)alloc(128 * 4);
  float* tr1     = (float*)alloc(256);
  size_t zeroB_len = (size_t)(w - (char*)pooled0);
  // CSR
  int* rp0  = (int*)alloc((NN + 1) * 4);
  int* cur0 = (int*)alloc(NN * 4);
  int* csr0 = (int*)alloc(EE * 4);
  int* rp1  = (int*)alloc((NN + 1) * 4);
  int* cur1 = (int*)alloc(NN * 4);
  int* csr1 = (int*)alloc(EE * 4);
  // transposed fp16 weights (12 x 128x128)
  f16* WT = (f16*)alloc(12 * 16384 * sizeof(f16));
  // fp16 feature buffers, 2 MB each; reuse by liveness:
  //  F1: x -> z -> ST       F2: agg -> t(mlp)      F3: h -> HT
  //  F4: h_final            F5: s
  f16* F1_0 = (f16*)alloc((size_t)NN * DD * 2);
  f16* F2_0 = (f16*)alloc((size_t)NN * DD * 2);
  f16* F3_0 = (f16*)alloc((size_t)NN * DD * 2);
  f16* F4_0 = (f16*)alloc((size_t)NN * DD * 2);
  f16* F5_0 = (f16*)alloc((size_t)NN * DD * 2);
  f16* F1_1 = (f16*)alloc((size_t)NN * DD * 2);
  f16* F2_1 = (f16*)alloc((size_t)NN * DD * 2);
  f16* F3_1 = (f16*)alloc((size_t)NN * DD * 2);
  f16* F4_1 = (f16*)alloc((size_t)NN * DD * 2);
  f16* F5_1 = (f16*)alloc((size_t)NN * DD * 2);

  hipMemsetAsync(cnt0, 0, zeroA_len, stream);
  hipMemsetAsync(pooled0, 0, zeroB_len, stream);
  hipMemsetAsync(out + 32768, 0, 4, stream);

  // weight transpose + CSR build
  wprep<<<12, 256, 0, stream>>>(c1_Wl, c1_Wr, c2_Wl, c2_Wr, co_Wl, co_Wr,
                                c3_Wl, c3_Wr, c4_Wl, c4_Wr, m_W1, m_W2, WT);
  count_kernel<<<dim3(256, 2), 256, 0, stream>>>(e1, e2, cnt0, deg0, cnt1, deg1);
  scan_kernel<<<2, 1024, 0, stream>>>(cnt0, cnt1, rp0, rp1, cur0, cur1);
  fill_csr<<<dim3(256, 2), 256, 0, stream>>>(e1, e2, cur0, cur1, csr0, csr1);

  // x -> fp16
  cast_kernel<<<dim3(512, 2), 256, 0, stream>>>(x1, x2, F1_0, F1_1);

  f16* W_c1l = WT;            f16* W_c1r = WT + 16384;
  f16* W_c2l = WT + 2*16384;  f16* W_c2r = WT + 3*16384;
  f16* W_col = WT + 4*16384;  f16* W_cor = WT + 5*16384;
  f16* W_c3l = WT + 6*16384;  f16* W_c3r = WT + 7*16384;
  f16* W_c4l = WT + 8*16384;  f16* W_c4r = WT + 9*16384;
  f16* W_m1  = WT + 10*16384; f16* W_m2  = WT + 11*16384;

  // sage1: h = mish(mean(x)@Wl + x@Wr + bl) -> F3
  agg_mean<<<dim3(512, 2), 256, 0, stream>>>(rp0, rp1, csr0, csr1, F1_0, F1_1, F2_0, F2_1);
  gemm_mfma<1, 1, 0><<<dim3(128, 2), 128, 0, stream>>>(F2_0, F2_1, F1_0, F1_1,
      W_c1l, W_c2l, W_c1r, W_c2r, c1_bl, c2_bl, nullptr, nullptr, F3_0, F3_1);

  // sage2 (shared co weights) fused with residual: z = h + mish(sage(h)) -> F1
  agg_mean<<<dim3(512, 2), 256, 0, stream>>>(rp0, rp1, csr0, csr1, F3_0, F3_1, F2_0, F2_1);
  gemm_mfma<1, 1, 1><<<dim3(128, 2), 128, 0, stream>>>(F2_0, F2_1, F3_0, F3_1,
      W_col, W_col, W_cor, W_cor, co_bl, co_bl, F3_0, F3_1, F1_0, F1_1);

  // sage3: h_final = mish(sage(z)) -> F4
  agg_mean<<<dim3(512, 2), 256, 0, stream>>>(rp0, rp1, csr0, csr1, F1_0, F1_1, F2_0, F2_1);
  gemm_mfma<1, 1, 0><<<dim3(128, 2), 128, 0, stream>>>(F2_0, F2_1, F1_0, F1_1,
      W_c3l, W_c4l, W_c3r, W_c4r, c3_bl, c4_bl, nullptr, nullptr, F4_0, F4_1);

  // dmon MLP: t = h@W1+b1 -> F2 ; s = softmax(t@W2+b2) -> F5
  gemm_mfma<0, 0, 0><<<dim3(128, 2), 128, 0, stream>>>(F4_0, F4_1, nullptr, nullptr,
      W_m1, W_m1, nullptr, nullptr, m_b1, m_b1, nullptr, nullptr, F2_0, F2_1);
  gemm_mfma<0, 2, 0><<<dim3(128, 2), 128, 0, stream>>>(F2_0, F2_1, nullptr, nullptr,
      W_m2, W_m2, nullptr, nullptr, m_b2, m_b2, nullptr, nullptr, F5_0, F5_1);

  // transpose S -> ST (F1), Hf -> HT (F3)
  transpose_kernel<<<dim3(256, 2, 2), 256, 0, stream>>>(
      F5_0, F5_1, F4_0, F4_1, F1_0, F1_1, F3_0, F3_1);

  // pooled = s^T h ; ss = s^T s  (MFMA split-K)
  pool_mfma<<<dim3(PK_NSPLIT, 2, 2), 256, 0, stream>>>(F1_0, F1_1, F3_0, F3_1,
      pooled0, pooled1, ss0, ss1);
  colca_kernel<<<dim3(128, 2), 256, 0, stream>>>(F1_0, F1_1, deg0, deg1,
      col0, col1, ca0, ca1);
  trace_kernel<<<dim3(512, 2), 256, 0, stream>>>(rp0, rp1, csr0, csr1, F5_0, F5_1, tr0, tr1);

  finalize_kernel<<<2, 256, 0, stream>>>(ss0, ss1, col0, col1, ca0, ca1, tr0, tr1,
      out + 32768);
  selu_kernel<<<dim3(64, 2), 256, 0, stream>>>(pooled0, pooled1, out);
}

// Round 6
// 306.367 us; speedup vs baseline: 2.6335x; 1.1370x over previous
//
#include <hip/hip_runtime.h>
#include <math.h>

#define NN 8192
#define DD 128
#define KK 128
#define EE 262144

typedef _Float16 f16;
typedef __attribute__((ext_vector_type(8))) _Float16 f16x8;
typedef __attribute__((ext_vector_type(4))) float f32x4;

// ---------------------------------------------------------------- activation
__device__ __forceinline__ float mishf(float v){
  float e  = __expf(v);
  float t2 = e * (e + 2.f);
  float r  = v * (t2 / (t2 + 2.f));
  return (v > 30.f) ? v : r;
}

// ---------------------------------------------------------------- cast x -> fp16
__global__ __launch_bounds__(256) void cast_kernel(
    const float* __restrict__ x0, const float* __restrict__ x1,
    f16* __restrict__ f0, f16* __restrict__ f1){
  int g = blockIdx.y;
  const float* x = g ? x1 : x0;
  f16* f = g ? f1 : f0;
  int idx = blockIdx.x * 256 + threadIdx.x;      // 8 floats/thread, 512 blocks
  const float4* p = (const float4*)&x[idx * 8];
  float4 a = p[0], b = p[1];
  f16x8 o;
  o[0] = (f16)a.x; o[1] = (f16)a.y; o[2] = (f16)a.z; o[3] = (f16)a.w;
  o[4] = (f16)b.x; o[5] = (f16)b.y; o[6] = (f16)b.z; o[7] = (f16)b.w;
  *(f16x8*)&f[idx * 8] = o;
}

// ---------------------------------------------------------------- weight prep: cast+transpose
__global__ __launch_bounds__(256) void wprep(
    const float* w0, const float* w1, const float* w2, const float* w3,
    const float* w4, const float* w5, const float* w6, const float* w7,
    const float* w8, const float* w9, const float* w10, const float* w11,
    f16* WT){
  const float* Ws[12] = {w0,w1,w2,w3,w4,w5,w6,w7,w8,w9,w10,w11};
  const float* W = Ws[blockIdx.x];
  f16* O = WT + (size_t)blockIdx.x * 16384;
  int t = threadIdx.x;
  int n = t >> 1, k0 = (t & 1) * 64;
#pragma unroll
  for (int seg = 0; seg < 8; ++seg){
    f16x8 o;
#pragma unroll
    for (int q = 0; q < 8; ++q)
      o[q] = (f16)W[(k0 + seg * 8 + q) * 128 + n];
    *(f16x8*)&O[n * 128 + k0 + seg * 8] = o;
  }
}

// ---------------------------------------------------------------- CSR build
__global__ __launch_bounds__(256) void count_kernel(
    const int* __restrict__ eA, const int* __restrict__ eB,
    int* cntA, int* degA, int* cntB, int* degB){
  int g = blockIdx.y;
  const int* e  = g ? eB : eA;
  int* cnt = g ? cntB : cntA;
  int* deg = g ? degB : degA;
  const int* src = e;
  const int* dst = e + EE;
  int stride = gridDim.x * blockDim.x;
  for (int i = blockIdx.x * blockDim.x + threadIdx.x; i < EE; i += stride){
    atomicAdd(&cnt[dst[i]], 1);
    atomicAdd(&deg[src[i]], 1);
  }
}

__global__ __launch_bounds__(1024) void scan_kernel(
    const int* cntA, const int* cntB, int* rpA, int* rpB, int* curA, int* curB){
  int g = blockIdx.x;
  const int* cnt = g ? cntB : cntA;
  int* rp  = g ? rpB : rpA;
  int* cur = g ? curB : curA;
  __shared__ int sums[1024];
  int t = threadIdx.x;
  int v[8];
  int base = t * 8;
  int tot = 0;
#pragma unroll
  for (int j = 0; j < 8; ++j){ v[j] = cnt[base + j]; tot += v[j]; }
  sums[t] = tot; __syncthreads();
  for (int off = 1; off < 1024; off <<= 1){
    int x = 0;
    if (t >= off) x = sums[t - off];
    __syncthreads();
    sums[t] += x;
    __syncthreads();
  }
  int run = (t == 0) ? 0 : sums[t - 1];
#pragma unroll
  for (int j = 0; j < 8; ++j){ rp[base + j] = run; cur[base + j] = run; run += v[j]; }
  if (t == 1023) rp[NN] = run;
}

__global__ __launch_bounds__(256) void fill_csr(
    const int* __restrict__ eA, const int* __restrict__ eB,
    int* curA, int* curB, int* csrA, int* csrB){
  int g = blockIdx.y;
  const int* e = g ? eB : eA;
  int* cur = g ? curB : curA;
  int* csr = g ? csrB : csrA;
  const int* src = e;
  const int* dst = e + EE;
  int stride = gridDim.x * blockDim.x;
  for (int i = blockIdx.x * blockDim.x + threadIdx.x; i < EE; i += stride){
    int pos = atomicAdd(&cur[dst[i]], 1);
    csr[pos] = src[i];
  }
}

// ---------------------------------------------------------------- mean-aggregate (fp16 gather, 4x unroll)
__global__ __launch_bounds__(256) void agg_mean(
    const int* __restrict__ rpA, const int* __restrict__ rpB,
    const int* __restrict__ csrA, const int* __restrict__ csrB,
    const f16* __restrict__ FA, const f16* __restrict__ FBp,
    f16* __restrict__ MA, f16* __restrict__ MB){
  int g = blockIdx.y;
  const int* rp  = g ? rpB  : rpA;
  const int* csr = g ? csrB : csrA;
  const f16* F = g ? FBp : FA;
  f16* M = g ? MB : MA;
  int t = threadIdx.x;
  int node = blockIdx.x * 16 + (t >> 4);
  int lane = t & 15;                      // 16 lanes x 8 elems = 128
  int beg = rp[node], end = rp[node + 1];
  float a[8];
#pragma unroll
  for (int k = 0; k < 8; ++k) a[k] = 0.f;
  int j = beg;
  for (; j + 4 <= end; j += 4){
    int s0 = csr[j], s1 = csr[j + 1], s2 = csr[j + 2], s3 = csr[j + 3];
    f16x8 v0 = *(const f16x8*)&F[s0 * DD + lane * 8];
    f16x8 v1 = *(const f16x8*)&F[s1 * DD + lane * 8];
    f16x8 v2 = *(const f16x8*)&F[s2 * DD + lane * 8];
    f16x8 v3 = *(const f16x8*)&F[s3 * DD + lane * 8];
#pragma unroll
    for (int k = 0; k < 8; ++k)
      a[k] += ((float)v0[k] + (float)v1[k]) + ((float)v2[k] + (float)v3[k]);
  }
  for (; j < end; ++j){
    int s = csr[j];
    f16x8 v = *(const f16x8*)&F[s * DD + lane * 8];
#pragma unroll
    for (int k = 0; k < 8; ++k) a[k] += (float)v[k];
  }
  float inv = 1.f / fmaxf((float)(end - beg), 1.f);
  f16x8 o;
#pragma unroll
  for (int k = 0; k < 8; ++k) o[k] = (f16)(a[k] * inv);
  *(f16x8*)&M[node * DD + lane * 8] = o;
}

// ---------------------------------------------------------------- MFMA GEMM [8192,128]@[128,128]
// O = ACT(A@Wa (+ B@Wb) + bias) (+ ADD for FUSEADD). W given transposed [n][k] fp16.
// Block: 128 thr = 2 waves; 64 rows/block (32/wave), full 128 cols, K=128.
template<int DUAL, int ACT, int FUSEADD>
__global__ __launch_bounds__(128) void gemm_mfma(
    const f16* __restrict__ A0, const f16* __restrict__ A1,
    const f16* __restrict__ B0, const f16* __restrict__ B1,
    const f16* __restrict__ WaT0, const f16* __restrict__ WaT1,
    const f16* __restrict__ WbT0, const f16* __restrict__ WbT1,
    const float* __restrict__ bi0, const float* __restrict__ bi1,
    const f16* __restrict__ ADD0, const f16* __restrict__ ADD1,
    f16* __restrict__ O0, f16* __restrict__ O1){
  int g = blockIdx.y;
  const f16* A   = g ? A1 : A0;
  const f16* B   = g ? B1 : B0;
  const f16* WaT = g ? WaT1 : WaT0;
  const f16* WbT = g ? WbT1 : WbT0;
  const float* bi = g ? bi1 : bi0;
  const f16* ADD = g ? ADD1 : ADD0;
  f16* O = g ? O1 : O0;

  int t = threadIdx.x;
  int wave = t >> 6, l = t & 63;
  int lrow = l & 15;
  int lk = (l >> 4) * 8;
  int rowBase = blockIdx.x * 64 + wave * 32;

  f32x4 acc[2][8];
#pragma unroll
  for (int rt = 0; rt < 2; ++rt)
#pragma unroll
    for (int nt = 0; nt < 8; ++nt)
      acc[rt][nt] = (f32x4){0.f, 0.f, 0.f, 0.f};

#pragma unroll
  for (int kc = 0; kc < 4; ++kc){
    int kb = kc * 32 + lk;
    f16x8 a0 = *(const f16x8*)&A[(rowBase + lrow) * 128 + kb];
    f16x8 a1 = *(const f16x8*)&A[(rowBase + 16 + lrow) * 128 + kb];
#pragma unroll
    for (int nt = 0; nt < 8; ++nt){
      f16x8 bw = *(const f16x8*)&WaT[(nt * 16 + lrow) * 128 + kb];
      acc[0][nt] = __builtin_amdgcn_mfma_f32_16x16x32_f16(a0, bw, acc[0][nt], 0, 0, 0);
      acc[1][nt] = __builtin_amdgcn_mfma_f32_16x16x32_f16(a1, bw, acc[1][nt], 0, 0, 0);
    }
    if (DUAL){
      f16x8 c0 = *(const f16x8*)&B[(rowBase + lrow) * 128 + kb];
      f16x8 c1 = *(const f16x8*)&B[(rowBase + 16 + lrow) * 128 + kb];
#pragma unroll
      for (int nt = 0; nt < 8; ++nt){
        f16x8 bw = *(const f16x8*)&WbT[(nt * 16 + lrow) * 128 + kb];
        acc[0][nt] = __builtin_amdgcn_mfma_f32_16x16x32_f16(c0, bw, acc[0][nt], 0, 0, 0);
        acc[1][nt] = __builtin_amdgcn_mfma_f32_16x16x32_f16(c1, bw, acc[1][nt], 0, 0, 0);
      }
    }
  }

  // epilogue: C/D layout col = l&15, row = (l>>4)*4 + r
  int col16 = l & 15;
  int rgrp = (l >> 4) * 4;
  float bv[8];
#pragma unroll
  for (int nt = 0; nt < 8; ++nt) bv[nt] = bi[nt * 16 + col16];

#pragma unroll
  for (int rt = 0; rt < 2; ++rt){
#pragma unroll
    for (int r = 0; r < 4; ++r){
      int row = rowBase + rt * 16 + rgrp + r;
      float v[8];
#pragma unroll
      for (int nt = 0; nt < 8; ++nt) v[nt] = acc[rt][nt][r] + bv[nt];
      if (ACT == 1){
#pragma unroll
        for (int nt = 0; nt < 8; ++nt) v[nt] = mishf(v[nt]);
      }
      if (ACT == 2){
        float m = v[0];
#pragma unroll
        for (int nt = 1; nt < 8; ++nt) m = fmaxf(m, v[nt]);
        for (int msk = 1; msk < 16; msk <<= 1) m = fmaxf(m, __shfl_xor(m, msk));
        float sum = 0.f;
#pragma unroll
        for (int nt = 0; nt < 8; ++nt){ v[nt] = __expf(v[nt] - m); sum += v[nt]; }
        for (int msk = 1; msk < 16; msk <<= 1) sum += __shfl_xor(sum, msk);
        float inv = 1.f / sum;
#pragma unroll
        for (int nt = 0; nt < 8; ++nt) v[nt] *= inv;
      }
      if (FUSEADD){
#pragma unroll
        for (int nt = 0; nt < 8; ++nt) v[nt] += (float)ADD[row * 128 + nt * 16 + col16];
      }
#pragma unroll
      for (int nt = 0; nt < 8; ++nt)
        O[row * 128 + nt * 16 + col16] = (f16)v[nt];
    }
  }
}

// ---------------------------------------------------------------- fp16 transpose [8192][128]->[128][8192]
__global__ __launch_bounds__(256) void transpose_kernel(
    const f16* __restrict__ in0A, const f16* __restrict__ in1A,   // z=0 src (S)
    const f16* __restrict__ in0B, const f16* __restrict__ in1B,   // z=1 src (Hf)
    f16* __restrict__ o0A, f16* __restrict__ o1A,
    f16* __restrict__ o0B, f16* __restrict__ o1B){
  int g = blockIdx.y, z = blockIdx.z;
  const f16* in = z ? (g ? in1B : in0B) : (g ? in1A : in0A);
  f16* outp     = z ? (g ? o1B  : o0B)  : (g ? o1A  : o0A);
  __shared__ f16 T[32][136];
  int t = threadIdx.x;
  int i0 = blockIdx.x * 32;
#pragma unroll
  for (int j = 0; j < 2; ++j){
    int idx = t + j * 256;
    int row = idx >> 4, c8 = (idx & 15) * 8;
    f16x8 v = *(const f16x8*)&in[(i0 + row) * 128 + c8];
#pragma unroll
    for (int q = 0; q < 8; ++q) T[row][c8 + q] = v[q];
  }
  __syncthreads();
  int k = t >> 1, seg = (t & 1) * 16;
  f16x8 oA, oB;
#pragma unroll
  for (int q = 0; q < 8; ++q){ oA[q] = T[seg + q][k]; oB[q] = T[seg + 8 + q][k]; }
  *(f16x8*)&outp[(size_t)k * NN + i0 + seg]     = oA;
  *(f16x8*)&outp[(size_t)k * NN + i0 + seg + 8] = oB;
}

// ---------------------------------------------------------------- pooled/ss via MFMA split-K
// OUT[r][c] = sum_i ST[r][i] * BT[c][i];  z=0: BT=HT -> pooled, z=1: BT=ST -> ss
#define PK_NSPLIT 16
__global__ __launch_bounds__(256) void pool_mfma(
    const f16* __restrict__ ST0, const f16* __restrict__ ST1,
    const f16* __restrict__ HT0, const f16* __restrict__ HT1,
    float* P0, float* P1, float* SS0, float* SS1){
  int g = blockIdx.y, z = blockIdx.z;
  const f16* A = g ? ST1 : ST0;
  const f16* B = z ? A : (g ? HT1 : HT0);
  float* OUT = z ? (g ? SS1 : SS0) : (g ? P1 : P0);

  int t = threadIdx.x;
  int wave = t >> 6, l = t & 63;
  int lrow = l & 15;
  int lk = (l >> 4) * 8;
  int krow = wave * 32;                   // output rows [krow, krow+32)
  int i0 = blockIdx.x * (NN / PK_NSPLIT); // K slab of 512

  f32x4 acc[2][8];
#pragma unroll
  for (int rt = 0; rt < 2; ++rt)
#pragma unroll
    for (int nt = 0; nt < 8; ++nt)
      acc[rt][nt] = (f32x4){0.f, 0.f, 0.f, 0.f};

#pragma unroll 2
  for (int c = 0; c < NN / PK_NSPLIT; c += 32){
    int ib = i0 + c + lk;
    f16x8 a0 = *(const f16x8*)&A[(size_t)(krow + lrow) * NN + ib];
    f16x8 a1 = *(const f16x8*)&A[(size_t)(krow + 16 + lrow) * NN + ib];
#pragma unroll
    for (int nt = 0; nt < 8; ++nt){
      f16x8 bf = *(const f16x8*)&B[(size_t)(nt * 16 + lrow) * NN + ib];
      acc[0][nt] = __builtin_amdgcn_mfma_f32_16x16x32_f16(a0, bf, acc[0][nt], 0, 0, 0);
      acc[1][nt] = __builtin_amdgcn_mfma_f32_16x16x32_f16(a1, bf, acc[1][nt], 0, 0, 0);
    }
  }

  int col = l & 15;
  int rbase = (l >> 4) * 4;
#pragma unroll
  for (int rt = 0; rt < 2; ++rt)
#pragma unroll
    for (int nt = 0; nt < 8; ++nt)
#pragma unroll
      for (int r = 0; r < 4; ++r)
        atomicAdd(&OUT[(krow + rt * 16 + rbase + r) * 128 + nt * 16 + col], acc[rt][nt][r]);
}

// ---------------------------------------------------------------- colsum + ca from ST
__global__ __launch_bounds__(256) void colca_kernel(
    const f16* __restrict__ ST0, const f16* __restrict__ ST1,
    const int* __restrict__ dg0, const int* __restrict__ dg1,
    float* col0, float* col1, float* ca0, float* ca1){
  int g = blockIdx.y;
  const f16* ST = g ? ST1 : ST0;
  const int* dg = g ? dg1 : dg0;
  float* col = g ? col1 : col0;
  float* ca  = g ? ca1  : ca0;
  int k = blockIdx.x;
  int t = threadIdx.x;
  float cs = 0.f, cc = 0.f;
  for (int i = t * 8; i < NN; i += 2048){
    f16x8 v = *(const f16x8*)&ST[(size_t)k * NN + i];
#pragma unroll
    for (int j = 0; j < 8; ++j){
      float f = (float)v[j];
      cs += f;
      cc += f * (float)dg[i + j];
    }
  }
  __shared__ float r1[256], r2[256];
  r1[t] = cs; r2[t] = cc; __syncthreads();
  for (int o = 128; o > 0; o >>= 1){
    if (t < o){ r1[t] += r1[t + o]; r2[t] += r2[t + o]; }
    __syncthreads();
  }
  if (t == 0){ col[k] = r1[0]; ca[k] = r2[0]; }
}

// ---------------------------------------------------------------- trace(s^T adj s) via CSR, fp16, 4x unroll
__global__ __launch_bounds__(256) void trace_kernel(
    const int* __restrict__ rpA, const int* __restrict__ rpB,
    const int* __restrict__ csrA, const int* __restrict__ csrB,
    const f16* __restrict__ SA, const f16* __restrict__ SBp,
    float* tr0, float* tr1){
  int g = blockIdx.y;
  const int* rp  = g ? rpB  : rpA;
  const int* csr = g ? csrB : csrA;
  const f16* S = g ? SBp : SA;
  float* tr = g ? tr1 : tr0;
  int t = threadIdx.x;
  int grp = t >> 4, lane = t & 15;
  int node = blockIdx.x * 16 + grp;
  int beg = rp[node], end = rp[node + 1];
  f16x8 w = *(const f16x8*)&S[node * DD + lane * 8];
  float o[8];
#pragma unroll
  for (int k = 0; k < 8; ++k) o[k] = (float)w[k];
  float acc = 0.f;
  int j = beg;
  for (; j + 4 <= end; j += 4){
    int s0 = csr[j], s1 = csr[j + 1], s2 = csr[j + 2], s3 = csr[j + 3];
    f16x8 v0 = *(const f16x8*)&S[s0 * DD + lane * 8];
    f16x8 v1 = *(const f16x8*)&S[s1 * DD + lane * 8];
    f16x8 v2 = *(const f16x8*)&S[s2 * DD + lane * 8];
    f16x8 v3 = *(const f16x8*)&S[s3 * DD + lane * 8];
#pragma unroll
    for (int k = 0; k < 8; ++k)
      acc += o[k] * (((float)v0[k] + (float)v1[k]) + ((float)v2[k] + (float)v3[k]));
  }
  for (; j < end; ++j){
    int s = csr[j];
    f16x8 v = *(const f16x8*)&S[s * DD + lane * 8];
#pragma unroll
    for (int k = 0; k < 8; ++k) acc += o[k] * (float)v[k];
  }
  for (int m = 1; m < 16; m <<= 1) acc += __shfl_xor(acc, m);
  __shared__ float part[16];
  if (lane == 0) part[grp] = acc;
  __syncthreads();
  if (t == 0){
    float s = 0.f;
#pragma unroll
    for (int i = 0; i < 16; ++i) s += part[i];
    atomicAdd(tr, s);
  }
}

// ---------------------------------------------------------------- losses
__device__ float block_reduce(float v, float* red, int t){
  red[t] = v; __syncthreads();
  for (int o = 128; o > 0; o >>= 1){
    if (t < o) red[t] += red[t + o];
    __syncthreads();
  }
  float r = red[0]; __syncthreads();
  return r;
}

__global__ __launch_bounds__(256) void finalize_kernel(
    const float* ss0, const float* ss1, const float* col0, const float* col1,
    const float* ca0, const float* ca1, const float* tr0, const float* tr1,
    float* loss_out){
  int g = blockIdx.x;
  const float* ss  = g ? ss1  : ss0;
  const float* col = g ? col1 : col0;
  const float* ca  = g ? ca1  : ca0;
  const float* tr  = g ? tr1  : tr0;
  __shared__ float red[256];
  int t = threadIdx.x;
  float s2 = 0.f;
  for (int i = t; i < 16384; i += 256){ float x = ss[i]; s2 += x * x; }
  float F2   = block_reduce(s2, red, t);
  float trss = block_reduce((t < 128) ? ss[t * 129] : 0.f, red, t);
  float ca2  = block_reduce((t < 128) ? ca[t] * ca[t] : 0.f, red, t);
  float cs2  = block_reduce((t < 128) ? col[t] * col[t] : 0.f, red, t);
  if (t == 0){
    float F = sqrtf(F2);
    float ortho = sqrtf(fmaxf(2.f - 2.f * trss / (F * sqrtf((float)KK)), 0.f));
    float m2 = (float)EE;                 // 2m
    float spectral = -(tr[0] - ca2 / m2) / m2;
    float cluster = sqrtf(cs2) / (float)NN * sqrtf((float)KK) - 1.f;
    atomicAdd(loss_out, spectral + ortho + cluster);
  }
}

// ---------------------------------------------------------------- selu + store pooled
__global__ __launch_bounds__(256) void selu_kernel(
    const float* p0, const float* p1, float* out){
  int g = blockIdx.y;
  const float* p = g ? p1 : p0;
  int idx = blockIdx.x * 256 + threadIdx.x;
  float v = p[idx];
  const float scale = 1.0507009873554805f, alpha = 1.6732632423543772f;
  float r = (v > 0.f) ? scale * v : scale * alpha * expm1f(v);
  out[g * 16384 + idx] = r;
}

// ---------------------------------------------------------------- launch
extern "C" void kernel_launch(void* const* d_in, const int* in_sizes, int n_in,
                              void* d_out, int out_size, void* d_ws, size_t ws_size,
                              hipStream_t stream){
  const float* x1 = (const float*)d_in[0];
  const float* x2 = (const float*)d_in[1];
  const int*   e1 = (const int*)d_in[2];
  const int*   e2 = (const int*)d_in[3];
  const float* c1_Wl = (const float*)d_in[4];
  const float* c1_bl = (const float*)d_in[5];
  const float* c1_Wr = (const float*)d_in[6];
  const float* c2_Wl = (const float*)d_in[7];
  const float* c2_bl = (const float*)d_in[8];
  const float* c2_Wr = (const float*)d_in[9];
  const float* co_Wl = (const float*)d_in[10];
  const float* co_bl = (const float*)d_in[11];
  const float* co_Wr = (const float*)d_in[12];
  const float* c3_Wl = (const float*)d_in[13];
  const float* c3_bl = (const float*)d_in[14];
  const float* c3_Wr = (const float*)d_in[15];
  const float* c4_Wl = (const float*)d_in[16];
  const float* c4_bl = (const float*)d_in[17];
  const float* c4_Wr = (const float*)d_in[18];
  const float* m_W1 = (const float*)d_in[19];
  const float* m_b1 = (const float*)d_in[20];
  const float* m_W2 = (const float*)d_in[21];
  const float* m_b2 = (const float*)d_in[22];
  float* out = (float*)d_out;

  char* w = (char*)d_ws;
  auto alloc = [&](size_t bytes) -> char* {
    char* p = w;
    w += (bytes + 255) / 256 * 256;
    return p;
  };
  // zero region A: counts
  int* cnt0 = (int*)alloc(NN * 4);
  int* deg0 = (int*)alloc(NN * 4);
  int* cnt1 = (int*)alloc(NN * 4);
  int* deg1 = (int*)alloc(NN * 4);
  size_t zeroA_len = (size_t)(w - (char*)cnt0);
  // zero region B: accumulators
  float* pooled0 = (float*)alloc(16384 * 4);
  float* ss0     = (float*)alloc(16384 * 4);
  float* col0    = (float*)alloc(128 * 4);
  float* ca0     = (float*)alloc(128 * 4);
  float* tr0     = (float*)alloc(256);
  float* pooled1 = (float*)alloc(16384 * 4);
  float* ss1     = (float*)alloc(16384 * 4);
  float* col1    = (float*)alloc(128 * 4);
  float* ca1     = (float*)alloc(128 * 4);
  float* tr1     = (float*)alloc(256);
  size_t zeroB_len = (size_t)(w - (char*)pooled0);
  // CSR
  int* rp0  = (int*)alloc((NN + 1) * 4);
  int* cur0 = (int*)alloc(NN * 4);
  int* csr0 = (int*)alloc(EE * 4);
  int* rp1  = (int*)alloc((NN + 1) * 4);
  int* cur1 = (int*)alloc(NN * 4);
  int* csr1 = (int*)alloc(EE * 4);
  // transposed fp16 weights (12 x 128x128)
  f16* WT = (f16*)alloc(12 * 16384 * sizeof(f16));
  // fp16 feature buffers, 2 MB each; reuse by liveness:
  //  F1: x -> z -> ST       F2: agg -> t(mlp)      F3: h -> HT
  //  F4: h_final            F5: s
  f16* F1_0 = (f16*)alloc((size_t)NN * DD * 2);
  f16* F2_0 = (f16*)alloc((size_t)NN * DD * 2);
  f16* F3_0 = (f16*)alloc((size_t)NN * DD * 2);
  f16* F4_0 = (f16*)alloc((size_t)NN * DD * 2);
  f16* F5_0 = (f16*)alloc((size_t)NN * DD * 2);
  f16* F1_1 = (f16*)alloc((size_t)NN * DD * 2);
  f16* F2_1 = (f16*)alloc((size_t)NN * DD * 2);
  f16* F3_1 = (f16*)alloc((size_t)NN * DD * 2);
  f16* F4_1 = (f16*)alloc((size_t)NN * DD * 2);
  f16* F5_1 = (f16*)alloc((size_t)NN * DD * 2);

  hipMemsetAsync(cnt0, 0, zeroA_len, stream);
  hipMemsetAsync(pooled0, 0, zeroB_len, stream);
  hipMemsetAsync(out + 32768, 0, 4, stream);

  // weight transpose + CSR build
  wprep<<<12, 256, 0, stream>>>(c1_Wl, c1_Wr, c2_Wl, c2_Wr, co_Wl, co_Wr,
                                c3_Wl, c3_Wr, c4_Wl, c4_Wr, m_W1, m_W2, WT);
  count_kernel<<<dim3(256, 2), 256, 0, stream>>>(e1, e2, cnt0, deg0, cnt1, deg1);
  scan_kernel<<<2, 1024, 0, stream>>>(cnt0, cnt1, rp0, rp1, cur0, cur1);
  fill_csr<<<dim3(256, 2), 256, 0, stream>>>(e1, e2, cur0, cur1, csr0, csr1);

  // x -> fp16
  cast_kernel<<<dim3(512, 2), 256, 0, stream>>>(x1, x2, F1_0, F1_1);

  f16* W_c1l = WT;            f16* W_c1r = WT + 16384;
  f16* W_c2l = WT + 2*16384;  f16* W_c2r = WT + 3*16384;
  f16* W_col = WT + 4*16384;  f16* W_cor = WT + 5*16384;
  f16* W_c3l = WT + 6*16384;  f16* W_c3r = WT + 7*16384;
  f16* W_c4l = WT + 8*16384;  f16* W_c4r = WT + 9*16384;
  f16* W_m1  = WT + 10*16384; f16* W_m2  = WT + 11*16384;

  // sage1: h = mish(mean(x)@Wl + x@Wr + bl) -> F3
  agg_mean<<<dim3(512, 2), 256, 0, stream>>>(rp0, rp1, csr0, csr1, F1_0, F1_1, F2_0, F2_1);
  gemm_mfma<1, 1, 0><<<dim3(128, 2), 128, 0, stream>>>(F2_0, F2_1, F1_0, F1_1,
      W_c1l, W_c2l, W_c1r, W_c2r, c1_bl, c2_bl, nullptr, nullptr, F3_0, F3_1);

  // sage2 (shared co weights) fused with residual: z = h + mish(sage(h)) -> F1
  agg_mean<<<dim3(512, 2), 256, 0, stream>>>(rp0, rp1, csr0, csr1, F3_0, F3_1, F2_0, F2_1);
  gemm_mfma<1, 1, 1><<<dim3(128, 2), 128, 0, stream>>>(F2_0, F2_1, F3_0, F3_1,
      W_col, W_col, W_cor, W_cor, co_bl, co_bl, F3_0, F3_1, F1_0, F1_1);

  // sage3: h_final = mish(sage(z)) -> F4
  agg_mean<<<dim3(512, 2), 256, 0, stream>>>(rp0, rp1, csr0, csr1, F1_0, F1_1, F2_0, F2_1);
  gemm_mfma<1, 1, 0><<<dim3(128, 2), 128, 0, stream>>>(F2_0, F2_1, F1_0, F1_1,
      W_c3l, W_c4l, W_c3r, W_c4r, c3_bl, c4_bl, nullptr, nullptr, F4_0, F4_1);

  // dmon MLP: t = h@W1+b1 -> F2 ; s = softmax(t@W2+b2) -> F5
  gemm_mfma<0, 0, 0><<<dim3(128, 2), 128, 0, stream>>>(F4_0, F4_1, nullptr, nullptr,
      W_m1, W_m1, nullptr, nullptr, m_b1, m_b1, nullptr, nullptr, F2_0, F2_1);
  gemm_mfma<0, 2, 0><<<dim3(128, 2), 128, 0, stream>>>(F2_0, F2_1, nullptr, nullptr,
      W_m2, W_m2, nullptr, nullptr, m_b2, m_b2, nullptr, nullptr, F5_0, F5_1);

  // transpose S -> ST (F1), Hf -> HT (F3)
  transpose_kernel<<<dim3(256, 2, 2), 256, 0, stream>>>(
      F5_0, F5_1, F4_0, F4_1, F1_0, F1_1, F3_0, F3_1);

  // pooled = s^T h ; ss = s^T s  (MFMA split-K)
  pool_mfma<<<dim3(PK_NSPLIT, 2, 2), 256, 0, stream>>>(F1_0, F1_1, F3_0, F3_1,
      pooled0, pooled1, ss0, ss1);
  colca_kernel<<<dim3(128, 2), 256, 0, stream>>>(F1_0, F1_1, deg0, deg1,
      col0, col1, ca0, ca1);
  trace_kernel<<<dim3(512, 2), 256, 0, stream>>>(rp0, rp1, csr0, csr1, F5_0, F5_1, tr0, tr1);

  finalize_kernel<<<2, 256, 0, stream>>>(ss0, ss1, col0, col1, ca0, ca1, tr0, tr1,
      out + 32768);
  selu_kernel<<<dim3(64, 2), 256, 0, stream>>>(pooled0, pooled1, out);
}